// Round 6
// baseline (314.459 us; speedup 1.0000x reference)
//
#include <hip/hip_runtime.h>

using short8 = __attribute__((ext_vector_type(8))) short;
using f32x4  = __attribute__((ext_vector_type(4))) float;

#define BSHIFT 9
#define BSIZE  512     // nodes per bucket
#define CAP    12288   // max edges per bucket region (mean 8192, sigma ~90)
#define CHUNK  4096    // edges per bin block

// ---------------- bf16 helpers ----------------

__device__ __forceinline__ float bf_lo(unsigned int v) {
    return __int_as_float((int)(v << 16));
}
__device__ __forceinline__ float bf_hi(unsigned int v) {
    return __int_as_float((int)(v & 0xffff0000u));
}
__device__ __forceinline__ unsigned int f2bf(float f) {
    unsigned int x = __float_as_uint(f);
    x += 0x7fffu + ((x >> 16) & 1u);  // round-to-nearest-even
    return x >> 16;
}
__device__ __forceinline__ unsigned int pack_bf2(float lo, float hi) {
    return f2bf(lo) | (f2bf(hi) << 16);
}

// ---------------- graph prep: bucket binning ----------------

__global__ __launch_bounds__(256) void bin_kernel(
    const int* __restrict__ src, const int* __restrict__ dst, int E,
    int2* __restrict__ region, int* __restrict__ bfill) {
    __shared__ int lcnt[256];
    __shared__ int loff[256];
    __shared__ int gbase[256];
    __shared__ int2 stage[CHUNK];
    __shared__ unsigned short bOf[CHUNK];

    int t = threadIdx.x;
    int e0 = blockIdx.x * CHUNK;
    int cnt = min(CHUNK, E - e0);

    lcnt[t] = 0;
    __syncthreads();

    int s_[16], d_[16], p_[16];
#pragma unroll
    for (int i = 0; i < 16; i++) {
        int e = t + i * 256;
        if (e < cnt) {
            int s = src[e0 + e], d = dst[e0 + e];
            s_[i] = s;
            d_[i] = d;
            p_[i] = atomicAdd(&lcnt[d >> BSHIFT], 1);
        } else {
            d_[i] = -1;
        }
    }
    __syncthreads();

    int v = lcnt[t];
    loff[t] = v;
    __syncthreads();
    for (int off = 1; off < 256; off <<= 1) {
        int u = (t >= off) ? loff[t - off] : 0;
        __syncthreads();
        loff[t] += u;
        __syncthreads();
    }
    int ex = loff[t] - v;
    __syncthreads();
    loff[t] = ex;
    gbase[t] = (v > 0) ? atomicAdd(&bfill[t], v) : 0;
    __syncthreads();

#pragma unroll
    for (int i = 0; i < 16; i++) {
        if (d_[i] >= 0) {
            int b = d_[i] >> BSHIFT;
            int j = loff[b] + p_[i];
            stage[j] = make_int2(s_[i], d_[i]);
            bOf[j] = (unsigned short)b;
        }
    }
    __syncthreads();

    for (int j = t; j < cnt; j += 256) {
        int b = bOf[j];
        int idx = gbase[b] + (j - loff[b]);
        if (idx < CAP) region[(size_t)b * CAP + idx] = stage[j];
    }
}

__global__ void bscan_kernel(const int* __restrict__ bfill, int* __restrict__ bbase,
                             int* __restrict__ row_ptr, int nbuck, int n) {
    __shared__ int sh[256];
    int t = threadIdx.x;
    int v = (t < nbuck) ? min(bfill[t], CAP) : 0;
    sh[t] = v;
    __syncthreads();
    for (int off = 1; off < 256; off <<= 1) {
        int u = (t >= off) ? sh[t - off] : 0;
        __syncthreads();
        sh[t] += u;
        __syncthreads();
    }
    if (t < nbuck) bbase[t] = sh[t] - v;
    if (t == nbuck - 1) row_ptr[n] = sh[t];
}

__global__ __launch_bounds__(512) void build_kernel(
    const int2* __restrict__ region, const int* __restrict__ bfill,
    const int* __restrict__ bbase, int* __restrict__ row_ptr, float* __restrict__ dinv,
    int* __restrict__ col, int n) {
    __shared__ int cnt[BSIZE];
    __shared__ int excl[BSIZE];
    __shared__ int fill[BSIZE];
    int b = blockIdx.x;
    int t = threadIdx.x;
    int base = b * BSIZE;
    int ecnt = min(bfill[b], CAP);
    int ebase = bbase[b];
    const int2* reg = region + (size_t)b * CAP;

    cnt[t] = 0;
    fill[t] = 0;
    __syncthreads();

    for (int i = t; i < ecnt; i += 512) atomicAdd(&cnt[reg[i].y - base], 1);
    __syncthreads();

    int v = cnt[t];
    excl[t] = v;
    __syncthreads();
    for (int off = 1; off < 512; off <<= 1) {
        int u = (t >= off) ? excl[t - off] : 0;
        __syncthreads();
        excl[t] += u;
        __syncthreads();
    }
    int ex = excl[t] - v;
    __syncthreads();
    excl[t] = ex;
    __syncthreads();

    int node = base + t;
    if (node < n) {
        row_ptr[node] = ebase + ex;
        dinv[node] = rsqrtf((float)(v + 1));  // +1 self loop
    }

    for (int i = t; i < ecnt; i += 512) {
        int2 sd = reg[i];
        int li = sd.y - base;
        int pos = atomicAdd(&fill[li], 1);
        col[ebase + excl[li] + pos] = sd.x;
    }
}

// ---------------- MFMA dense transform: Y[n x NCOL](bf16) = (X[n x 128] @ W) * dinv[row] ----
// Swapped operands: A = W^T fragment (LDS, XOR-swizzled), B = X-row fragment (global).
// Epilogue scales each output row by dinv[row] (folds GCN's src-side norm into tmp').

template <int NCOL, bool XF32>
__global__ __launch_bounds__(256) void mfma_gemm_kernel(const void* __restrict__ Xv,
                                                        const float* __restrict__ W,
                                                        const float* __restrict__ dinv,
                                                        unsigned int* __restrict__ Y, int n) {
    constexpr int CF = NCOL / 16;
    __shared__ unsigned short Wt[(size_t)NCOL * 128];  // [c][k] bf16, swizzled

    int t = threadIdx.x;
    for (int i = t; i < 128 * NCOL; i += 256) {
        int k = i / NCOL, c = i % NCOL;
        int byte = (c * 256 + k * 2) ^ ((c & 7) << 4);
        Wt[byte >> 1] = (unsigned short)f2bf(W[i]);
    }
    __syncthreads();

    int wid = t >> 6, l = t & 63;
    int row0 = blockIdx.x * 64 + wid * 16;
    int xr = row0 + (l & 15);
    int xrc = min(xr, n - 1);
    int kq = l >> 4;

    f32x4 acc[CF];
#pragma unroll
    for (int cf = 0; cf < CF; cf++) acc[cf] = (f32x4){0.f, 0.f, 0.f, 0.f};

    const char* Wb = (const char*)Wt;

#pragma unroll
    for (int ks = 0; ks < 4; ks++) {
        short8 bq;
        if (XF32) {
            const float* Xf = (const float*)Xv + (size_t)xrc * 128 + ks * 32 + kq * 8;
            float4 x0 = ((const float4*)Xf)[0];
            float4 x1 = ((const float4*)Xf)[1];
            unsigned int p0 = pack_bf2(x0.x, x0.y), p1 = pack_bf2(x0.z, x0.w);
            unsigned int p2 = pack_bf2(x1.x, x1.y), p3 = pack_bf2(x1.z, x1.w);
            uint4 u = make_uint4(p0, p1, p2, p3);
            bq = *(const short8*)&u;
        } else {
            const char* Xb = (const char*)Xv + (size_t)xrc * 256 + ks * 64 + kq * 16;
            bq = *(const short8*)Xb;
        }
#pragma unroll
        for (int cf = 0; cf < CF; cf++) {
            int c = cf * 16 + (l & 15);
            int byte = (c * 256 + ks * 64 + kq * 16) ^ ((c & 7) << 4);
            short8 aq = *(const short8*)(Wb + byte);
            acc[cf] = __builtin_amdgcn_mfma_f32_16x16x32_bf16(aq, bq, acc[cf], 0, 0, 0);
        }
    }

    if (xr < n) {
        float dsc = dinv[xr];
        unsigned int* Yr = Y + (size_t)xr * (NCOL / 2);
#pragma unroll
        for (int cf = 0; cf < CF; cf++) {
            uint2 o = make_uint2(pack_bf2(acc[cf][0] * dsc, acc[cf][1] * dsc),
                                 pack_bf2(acc[cf][2] * dsc, acc[cf][3] * dsc));
            *(uint2*)(Yr + cf * 8 + kq * 2) = o;
        }
    }
}

// ---------------- fused aggregate + bias + LayerNorm + ReLU (128 bf16 features) -------------
// tmp rows pre-scaled by dinv[src]. Half-wave h streams edges beg+h, beg+h+2, ...
// lane (l=lane&31) holds features 4l..4l+3 (one uint2 = 4 bf16). out = di*sum + bias -> LN.

__global__ __launch_bounds__(256) void agg_ln_kernel(
    const unsigned int* __restrict__ tmp, const int* __restrict__ row_ptr,
    const int* __restrict__ col, const float* __restrict__ dinv,
    const float* __restrict__ bias, const float* __restrict__ gamma,
    const float* __restrict__ beta, unsigned int* __restrict__ out, int n) {
    int wid = threadIdx.x >> 6;
    int lane = threadIdx.x & 63;
    int half = lane >> 5;
    int l = lane & 31;
    int node = blockIdx.x * 4 + wid;
    if (node >= n) return;

    float di = dinv[node];
    int beg = __builtin_amdgcn_readfirstlane(row_ptr[node]);
    int end = __builtin_amdgcn_readfirstlane(row_ptr[node + 1]);

    const uint2* T = (const uint2*)tmp;  // row stride 32 uint2
    float a0 = 0.f, a1 = 0.f, a2 = 0.f, a3 = 0.f;
#pragma unroll 4
    for (int e = beg + half; e < end; e += 2) {
        int s = col[e];
        uint2 v = T[(size_t)s * 32 + l];
        a0 += bf_lo(v.x);
        a1 += bf_hi(v.x);
        a2 += bf_lo(v.y);
        a3 += bf_hi(v.y);
    }
    if (half == 0) {  // self loop
        uint2 v = T[(size_t)node * 32 + l];
        a0 += bf_lo(v.x);
        a1 += bf_hi(v.x);
        a2 += bf_lo(v.y);
        a3 += bf_hi(v.y);
    }
    // combine halves (both halves end with the full sum)
    a0 += __shfl_xor(a0, 32, 64);
    a1 += __shfl_xor(a1, 32, 64);
    a2 += __shfl_xor(a2, 32, 64);
    a3 += __shfl_xor(a3, 32, 64);

    float4 bb = ((const float4*)bias)[l];
    a0 = fmaf(a0, di, bb.x);
    a1 = fmaf(a1, di, bb.y);
    a2 = fmaf(a2, di, bb.z);
    a3 = fmaf(a3, di, bb.w);

    // LayerNorm: reduce within each 32-lane half (halves hold identical data)
    float s4 = a0 + a1 + a2 + a3;
#pragma unroll
    for (int m = 1; m < 32; m <<= 1) s4 += __shfl_xor(s4, m, 64);
    float mu = s4 * (1.0f / 128.0f);
    float d0 = a0 - mu, d1 = a1 - mu, d2 = a2 - mu, d3 = a3 - mu;
    float vv = d0 * d0 + d1 * d1 + d2 * d2 + d3 * d3;
#pragma unroll
    for (int m = 1; m < 32; m <<= 1) vv += __shfl_xor(vv, m, 64);
    float r = rsqrtf(vv * (1.0f / 128.0f) + 1e-5f);

    if (half == 0) {
        float4 gg = ((const float4*)gamma)[l];
        float4 be = ((const float4*)beta)[l];
        float o0 = fmaxf(fmaf(d0 * r, gg.x, be.x), 0.f);
        float o1 = fmaxf(fmaf(d1 * r, gg.y, be.y), 0.f);
        float o2 = fmaxf(fmaf(d2 * r, gg.z, be.z), 0.f);
        float o3 = fmaxf(fmaf(d3 * r, gg.w, be.w), 0.f);
        ((uint2*)out)[(size_t)node * 32 + l] = make_uint2(pack_bf2(o0, o1), pack_bf2(o2, o3));
    }
}

// ---------------- final aggregate + bias (64 bf16 features, no LN) ----------------
// Quarter-wave q streams edges beg+q, beg+q+4, ... lane (l=lane&15) holds features 4l..4l+3.

__global__ __launch_bounds__(256) void agg64_kernel(
    const unsigned int* __restrict__ tmp, const int* __restrict__ row_ptr,
    const int* __restrict__ col, const float* __restrict__ dinv,
    const float* __restrict__ bias, float* __restrict__ out, int n) {
    int wid = threadIdx.x >> 6;
    int lane = threadIdx.x & 63;
    int q = lane >> 4;
    int l = lane & 15;
    int node = blockIdx.x * 4 + wid;
    if (node >= n) return;

    float di = dinv[node];
    int beg = __builtin_amdgcn_readfirstlane(row_ptr[node]);
    int end = __builtin_amdgcn_readfirstlane(row_ptr[node + 1]);

    const uint2* T = (const uint2*)tmp;  // row stride 16 uint2
    float a0 = 0.f, a1 = 0.f, a2 = 0.f, a3 = 0.f;
#pragma unroll 4
    for (int e = beg + q; e < end; e += 4) {
        int s = col[e];
        uint2 v = T[(size_t)s * 16 + l];
        a0 += bf_lo(v.x);
        a1 += bf_hi(v.x);
        a2 += bf_lo(v.y);
        a3 += bf_hi(v.y);
    }
    if (q == 0) {  // self loop
        uint2 v = T[(size_t)node * 16 + l];
        a0 += bf_lo(v.x);
        a1 += bf_hi(v.x);
        a2 += bf_lo(v.y);
        a3 += bf_hi(v.y);
    }
    a0 += __shfl_xor(a0, 16, 64);
    a1 += __shfl_xor(a1, 16, 64);
    a2 += __shfl_xor(a2, 16, 64);
    a3 += __shfl_xor(a3, 16, 64);
    a0 += __shfl_xor(a0, 32, 64);
    a1 += __shfl_xor(a1, 32, 64);
    a2 += __shfl_xor(a2, 32, 64);
    a3 += __shfl_xor(a3, 32, 64);

    if (lane < 16) {
        float4 bb = ((const float4*)bias)[l];
        float4 o;
        o.x = fmaf(a0, di, bb.x);
        o.y = fmaf(a1, di, bb.y);
        o.z = fmaf(a2, di, bb.z);
        o.w = fmaf(a3, di, bb.w);
        ((float4*)out)[(size_t)node * 16 + l] = o;
    }
}

// ---------------- launch ----------------

extern "C" void kernel_launch(void* const* d_in, const int* in_sizes, int n_in,
                              void* d_out, int out_size, void* d_ws, size_t ws_size,
                              hipStream_t stream) {
    const float* x   = (const float*)d_in[0];
    const int*   ei  = (const int*)d_in[1];
    const float* W1  = (const float*)d_in[2];
    const float* b1  = (const float*)d_in[3];
    const float* g1  = (const float*)d_in[4];
    const float* be1 = (const float*)d_in[5];
    const float* W2  = (const float*)d_in[6];
    const float* b2  = (const float*)d_in[7];
    const float* g2  = (const float*)d_in[8];
    const float* be2 = (const float*)d_in[9];
    const float* W3  = (const float*)d_in[10];
    const float* b3  = (const float*)d_in[11];

    int n = in_sizes[0] / 128;
    int E = in_sizes[1] / 2;
    const int* src = ei;
    const int* dst = ei + E;
    int nbuck = (n + BSIZE - 1) / BSIZE;  // 196 for n=100000 (must be <= 256)

    char* p = (char*)d_ws;
    auto alloc = [&](size_t bytes) {
        void* q = (void*)p;
        p += (bytes + 255) & ~(size_t)255;
        return q;
    };
    int*   bfill   = (int*)alloc(256 * 4);
    int*   bbase   = (int*)alloc(256 * 4);
    int*   row_ptr = (int*)alloc((size_t)(n + 1) * 4);
    float* dinv    = (float*)alloc((size_t)n * 4);
    int2*  region  = (int2*)alloc((size_t)nbuck * CAP * 8);
    int*   col     = (int*)alloc((size_t)E * 4);
    unsigned int* bufA = (unsigned int*)alloc((size_t)n * 64 * 4);  // LN out, n x 128 bf16
    unsigned int* bufB = (unsigned int*)alloc((size_t)n * 64 * 4);  // GEMM out (dinv-scaled)

    hipMemsetAsync(bfill, 0, 256 * 4, stream);

    int bin_blocks = (E + CHUNK - 1) / CHUNK;
    bin_kernel<<<bin_blocks, 256, 0, stream>>>(src, dst, E, region, bfill);
    bscan_kernel<<<1, 256, 0, stream>>>(bfill, bbase, row_ptr, nbuck, n);
    build_kernel<<<nbuck, 512, 0, stream>>>(region, bfill, bbase, row_ptr, dinv, col, n);

    int gemm_blocks = (n + 63) / 64;
    int agg_blocks = (n + 3) / 4;

    // layer 1
    mfma_gemm_kernel<128, true><<<gemm_blocks, 256, 0, stream>>>(x, W1, dinv, bufB, n);
    agg_ln_kernel<<<agg_blocks, 256, 0, stream>>>(bufB, row_ptr, col, dinv, b1, g1, be1, bufA, n);

    // layer 2
    mfma_gemm_kernel<128, false><<<gemm_blocks, 256, 0, stream>>>(bufA, W2, dinv, bufB, n);
    agg_ln_kernel<<<agg_blocks, 256, 0, stream>>>(bufB, row_ptr, col, dinv, b2, g2, be2, bufA, n);

    // layer 3
    mfma_gemm_kernel<64, false><<<gemm_blocks, 256, 0, stream>>>(bufA, W3, dinv, bufB, n);
    agg64_kernel<<<agg_blocks, 256, 0, stream>>>(bufB, row_ptr, col, dinv, b3, (float*)d_out, n);
}

// Round 7
// 277.199 us; speedup vs baseline: 1.1344x; 1.1344x over previous
//
#include <hip/hip_runtime.h>

using short8 = __attribute__((ext_vector_type(8))) short;
using f32x4  = __attribute__((ext_vector_type(4))) float;

#define BSHIFT 9
#define BSIZE  512     // nodes per bucket
#define CAP    12288   // max edges per bucket region (mean 8192)
#define CHUNK  2048    // edges per bin block

// ---------------- bf16 helpers ----------------

__device__ __forceinline__ float bf_lo(unsigned int v) {
    return __int_as_float((int)(v << 16));
}
__device__ __forceinline__ float bf_hi(unsigned int v) {
    return __int_as_float((int)(v & 0xffff0000u));
}
__device__ __forceinline__ unsigned int f2bf(float f) {
    unsigned int x = __float_as_uint(f);
    x += 0x7fffu + ((x >> 16) & 1u);  // round-to-nearest-even
    return x >> 16;
}
__device__ __forceinline__ unsigned int pack_bf2(float lo, float hi) {
    return f2bf(lo) | (f2bf(hi) << 16);
}

// ---------------- weight pre-convert: fp32 -> bf16, XOR-swizzled [c][k] ----------------
// byte = (c*256 + k*2) ^ ((c&7)<<4)

__global__ void wconv_kernel(const float* __restrict__ W1, const float* __restrict__ W2,
                             const float* __restrict__ W3, unsigned short* __restrict__ o1,
                             unsigned short* __restrict__ o2, unsigned short* __restrict__ o3) {
    int i = blockIdx.x * 256 + threadIdx.x;
    const float* W;
    unsigned short* o;
    int ncol, j;
    if (i < 16384)      { W = W1; o = o1; ncol = 128; j = i; }
    else if (i < 32768) { W = W2; o = o2; ncol = 128; j = i - 16384; }
    else if (i < 40960) { W = W3; o = o3; ncol = 64;  j = i - 32768; }
    else return;
    int k = j / ncol, c = j % ncol;
    int byte = (c * 256 + k * 2) ^ ((c & 7) << 4);
    o[byte >> 1] = (unsigned short)f2bf(W[j]);
}

// ---------------- graph prep: bucket binning ----------------

__global__ __launch_bounds__(256) void bin_kernel(
    const int* __restrict__ src, const int* __restrict__ dst, int E,
    int2* __restrict__ region, int* __restrict__ bfill) {
    __shared__ int lcnt[256];
    __shared__ int loff[256];
    __shared__ int gbase[256];
    __shared__ int2 stage[CHUNK];
    __shared__ unsigned short bOf[CHUNK];

    int t = threadIdx.x;
    int e0 = blockIdx.x * CHUNK;
    int cnt = min(CHUNK, E - e0);

    lcnt[t] = 0;
    __syncthreads();

    int s_[8], d_[8], p_[8];
#pragma unroll
    for (int i = 0; i < 8; i++) {
        int e = t + i * 256;
        if (e < cnt) {
            int s = src[e0 + e], d = dst[e0 + e];
            s_[i] = s;
            d_[i] = d;
            p_[i] = atomicAdd(&lcnt[d >> BSHIFT], 1);
        } else {
            d_[i] = -1;
        }
    }
    __syncthreads();

    int v = lcnt[t];
    loff[t] = v;
    __syncthreads();
    for (int off = 1; off < 256; off <<= 1) {
        int u = (t >= off) ? loff[t - off] : 0;
        __syncthreads();
        loff[t] += u;
        __syncthreads();
    }
    int ex = loff[t] - v;
    __syncthreads();
    loff[t] = ex;
    gbase[t] = (v > 0) ? atomicAdd(&bfill[t], v) : 0;
    __syncthreads();

#pragma unroll
    for (int i = 0; i < 8; i++) {
        if (d_[i] >= 0) {
            int b = d_[i] >> BSHIFT;
            int j = loff[b] + p_[i];
            stage[j] = make_int2(s_[i], d_[i]);
            bOf[j] = (unsigned short)b;
        }
    }
    __syncthreads();

    for (int j = t; j < cnt; j += 256) {
        int b = bOf[j];
        int idx = gbase[b] + (j - loff[b]);
        if (idx < CAP) region[(size_t)b * CAP + idx] = stage[j];
    }
}

__global__ void bscan_kernel(const int* __restrict__ bfill, int* __restrict__ bbase,
                             int* __restrict__ row_ptr, int nbuck, int n) {
    __shared__ int sh[256];
    int t = threadIdx.x;
    int v = (t < nbuck) ? min(bfill[t], CAP) : 0;
    sh[t] = v;
    __syncthreads();
    for (int off = 1; off < 256; off <<= 1) {
        int u = (t >= off) ? sh[t - off] : 0;
        __syncthreads();
        sh[t] += u;
        __syncthreads();
    }
    if (t < nbuck) bbase[t] = sh[t] - v;
    if (t == nbuck - 1) row_ptr[n] = sh[t];
}

__global__ __launch_bounds__(512) void build_kernel(
    const int2* __restrict__ region, const int* __restrict__ bfill,
    const int* __restrict__ bbase, int* __restrict__ row_ptr, float* __restrict__ dinv,
    int* __restrict__ col, int n) {
    __shared__ int cnt[BSIZE];
    __shared__ int excl[BSIZE];
    __shared__ int fill[BSIZE];
    int b = blockIdx.x;
    int t = threadIdx.x;
    int base = b * BSIZE;
    int ecnt = min(bfill[b], CAP);
    int ebase = bbase[b];
    const int2* reg = region + (size_t)b * CAP;

    cnt[t] = 0;
    fill[t] = 0;
    __syncthreads();

    for (int i = t; i < ecnt; i += 512) atomicAdd(&cnt[reg[i].y - base], 1);
    __syncthreads();

    int v = cnt[t];
    excl[t] = v;
    __syncthreads();
    for (int off = 1; off < 512; off <<= 1) {
        int u = (t >= off) ? excl[t - off] : 0;
        __syncthreads();
        excl[t] += u;
        __syncthreads();
    }
    int ex = excl[t] - v;
    __syncthreads();
    excl[t] = ex;
    __syncthreads();

    int node = base + t;
    if (node < n) {
        row_ptr[node] = ebase + ex;
        dinv[node] = rsqrtf((float)(v + 1));  // +1 self loop
    }

    for (int i = t; i < ecnt; i += 512) {
        int2 sd = reg[i];
        int li = sd.y - base;
        int pos = atomicAdd(&fill[li], 1);
        col[ebase + excl[li] + pos] = sd.x;
    }
}

// ---------------- MFMA dense transform: Y[n x NCOL](bf16) = (X @ W) * dinv[row] -------------
// W pre-converted bf16 + swizzled. 128 rows per block (4 waves x 2 row-tiles of 16).

template <int NCOL, bool XF32>
__global__ __launch_bounds__(256) void mfma_gemm_kernel(const void* __restrict__ Xv,
                                                        const unsigned short* __restrict__ Wsw,
                                                        const float* __restrict__ dinv,
                                                        unsigned int* __restrict__ Y, int n) {
    constexpr int CF = NCOL / 16;
    __shared__ unsigned short Wt[(size_t)NCOL * 128];

    int t = threadIdx.x;
    {   // flat copy of pre-swizzled W (NCOL*16 uint4)
        const uint4* Wg = (const uint4*)Wsw;
        uint4* Wl = (uint4*)Wt;
        for (int i = t; i < NCOL * 16; i += 256) Wl[i] = Wg[i];
    }
    __syncthreads();

    int wid = t >> 6, l = t & 63;
    int row0 = blockIdx.x * 128;
    int kq = l >> 4;
    const char* Wb = (const char*)Wt;

    for (int rt = 0; rt < 2; rt++) {
        int xr = row0 + (wid * 2 + rt) * 16 + (l & 15);
        int xrc = min(xr, n - 1);

        f32x4 acc[CF];
#pragma unroll
        for (int cf = 0; cf < CF; cf++) acc[cf] = (f32x4){0.f, 0.f, 0.f, 0.f};

#pragma unroll
        for (int ks = 0; ks < 4; ks++) {
            short8 bq;
            if (XF32) {
                const float* Xf = (const float*)Xv + (size_t)xrc * 128 + ks * 32 + kq * 8;
                float4 x0 = ((const float4*)Xf)[0];
                float4 x1 = ((const float4*)Xf)[1];
                unsigned int p0 = pack_bf2(x0.x, x0.y), p1 = pack_bf2(x0.z, x0.w);
                unsigned int p2 = pack_bf2(x1.x, x1.y), p3 = pack_bf2(x1.z, x1.w);
                uint4 u = make_uint4(p0, p1, p2, p3);
                bq = *(const short8*)&u;
            } else {
                const char* Xb = (const char*)Xv + (size_t)xrc * 256 + ks * 64 + kq * 16;
                bq = *(const short8*)Xb;
            }
#pragma unroll
            for (int cf = 0; cf < CF; cf++) {
                int c = cf * 16 + (l & 15);
                int byte = (c * 256 + ks * 64 + kq * 16) ^ ((c & 7) << 4);
                short8 aq = *(const short8*)(Wb + byte);
                acc[cf] = __builtin_amdgcn_mfma_f32_16x16x32_bf16(aq, bq, acc[cf], 0, 0, 0);
            }
        }

        if (xr < n) {
            float dsc = dinv[xr];
            unsigned int* Yr = Y + (size_t)xr * (NCOL / 2);
#pragma unroll
            for (int cf = 0; cf < CF; cf++) {
                uint2 o = make_uint2(pack_bf2(acc[cf][0] * dsc, acc[cf][1] * dsc),
                                     pack_bf2(acc[cf][2] * dsc, acc[cf][3] * dsc));
                *(uint2*)(Yr + cf * 8 + kq * 2) = o;
            }
        }
    }
}

// ---------------- fused aggregate + bias + LayerNorm + ReLU (128 bf16 features) -------------
// tmp rows pre-scaled by dinv[src]. Uniform (scalar) col loads: 2 indices per iter,
// half-wave h takes index h. Grid-stride over nodes.

__global__ __launch_bounds__(256) void agg_ln_kernel(
    const unsigned int* __restrict__ tmp, const int* __restrict__ row_ptr,
    const int* __restrict__ col, const float* __restrict__ dinv,
    const float* __restrict__ bias, const float* __restrict__ gamma,
    const float* __restrict__ beta, unsigned int* __restrict__ out, int n) {
    int wid = threadIdx.x >> 6;
    int lane = threadIdx.x & 63;
    int half = lane >> 5;
    int l = lane & 31;
    int stride = gridDim.x * 4;

    const uint2* T = (const uint2*)tmp;  // row stride 32 uint2

    for (int node = blockIdx.x * 4 + wid; node < n; node += stride) {
        float di = dinv[node];
        int beg = __builtin_amdgcn_readfirstlane(row_ptr[node]);
        int end = __builtin_amdgcn_readfirstlane(row_ptr[node + 1]);

        float a0 = 0.f, a1 = 0.f, a2 = 0.f, a3 = 0.f;
        int e = beg;
#pragma unroll 4
        for (; e + 1 < end; e += 2) {
            int c0 = col[e];      // uniform -> scalar load
            int c1 = col[e + 1];
            int s = half ? c1 : c0;
            uint2 v = T[(size_t)s * 32 + l];
            a0 += bf_lo(v.x);
            a1 += bf_hi(v.x);
            a2 += bf_lo(v.y);
            a3 += bf_hi(v.y);
        }
        if (half == 1) {  // self loop on half 1 (odd tail goes to half 0)
            uint2 v = T[(size_t)node * 32 + l];
            a0 += bf_lo(v.x);
            a1 += bf_hi(v.x);
            a2 += bf_lo(v.y);
            a3 += bf_hi(v.y);
        }
        if (e < end && half == 0) {  // odd tail edge
            int s = col[e];
            uint2 v = T[(size_t)s * 32 + l];
            a0 += bf_lo(v.x);
            a1 += bf_hi(v.x);
            a2 += bf_lo(v.y);
            a3 += bf_hi(v.y);
        }
        // combine halves
        a0 += __shfl_xor(a0, 32, 64);
        a1 += __shfl_xor(a1, 32, 64);
        a2 += __shfl_xor(a2, 32, 64);
        a3 += __shfl_xor(a3, 32, 64);

        float4 bb = ((const float4*)bias)[l];
        a0 = fmaf(a0, di, bb.x);
        a1 = fmaf(a1, di, bb.y);
        a2 = fmaf(a2, di, bb.z);
        a3 = fmaf(a3, di, bb.w);

        // LayerNorm (reduce within each 32-lane half; halves identical)
        float s4 = a0 + a1 + a2 + a3;
#pragma unroll
        for (int m = 1; m < 32; m <<= 1) s4 += __shfl_xor(s4, m, 64);
        float mu = s4 * (1.0f / 128.0f);
        float d0 = a0 - mu, d1 = a1 - mu, d2 = a2 - mu, d3 = a3 - mu;
        float vv = d0 * d0 + d1 * d1 + d2 * d2 + d3 * d3;
#pragma unroll
        for (int m = 1; m < 32; m <<= 1) vv += __shfl_xor(vv, m, 64);
        float r = rsqrtf(vv * (1.0f / 128.0f) + 1e-5f);

        if (half == 0) {
            float4 gg = ((const float4*)gamma)[l];
            float4 be = ((const float4*)beta)[l];
            float o0 = fmaxf(fmaf(d0 * r, gg.x, be.x), 0.f);
            float o1 = fmaxf(fmaf(d1 * r, gg.y, be.y), 0.f);
            float o2 = fmaxf(fmaf(d2 * r, gg.z, be.z), 0.f);
            float o3 = fmaxf(fmaf(d3 * r, gg.w, be.w), 0.f);
            ((uint2*)out)[(size_t)node * 32 + l] = make_uint2(pack_bf2(o0, o1), pack_bf2(o2, o3));
        }
    }
}

// ---------------- final aggregate + bias (64 bf16 features, no LN) ----------------
// Quarter-wave q; uniform col loads 4 per iter; grid-stride.

__global__ __launch_bounds__(256) void agg64_kernel(
    const unsigned int* __restrict__ tmp, const int* __restrict__ row_ptr,
    const int* __restrict__ col, const float* __restrict__ dinv,
    const float* __restrict__ bias, float* __restrict__ out, int n) {
    int wid = threadIdx.x >> 6;
    int lane = threadIdx.x & 63;
    int q = lane >> 4;
    int l = lane & 15;
    int stride = gridDim.x * 4;

    const uint2* T = (const uint2*)tmp;  // row stride 16 uint2

    for (int node = blockIdx.x * 4 + wid; node < n; node += stride) {
        float di = dinv[node];
        int beg = __builtin_amdgcn_readfirstlane(row_ptr[node]);
        int end = __builtin_amdgcn_readfirstlane(row_ptr[node + 1]);

        float a0 = 0.f, a1 = 0.f, a2 = 0.f, a3 = 0.f;
        int e = beg;
#pragma unroll 2
        for (; e + 3 < end; e += 4) {
            int c0 = col[e], c1 = col[e + 1], c2 = col[e + 2], c3 = col[e + 3];
            int sa = (q & 1) ? c1 : c0;
            int sb = (q & 1) ? c3 : c2;
            int s = (q & 2) ? sb : sa;
            uint2 v = T[(size_t)s * 16 + l];
            a0 += bf_lo(v.x);
            a1 += bf_hi(v.x);
            a2 += bf_lo(v.y);
            a3 += bf_hi(v.y);
        }
        int rem = end - e;  // 0..3, so q==3 never takes a tail edge
        if (q < rem) {
            int s = col[e + q];
            uint2 v = T[(size_t)s * 16 + l];
            a0 += bf_lo(v.x);
            a1 += bf_hi(v.x);
            a2 += bf_lo(v.y);
            a3 += bf_hi(v.y);
        }
        if (q == 3) {  // self loop
            uint2 v = T[(size_t)node * 16 + l];
            a0 += bf_lo(v.x);
            a1 += bf_hi(v.x);
            a2 += bf_lo(v.y);
            a3 += bf_hi(v.y);
        }
        a0 += __shfl_xor(a0, 16, 64);
        a1 += __shfl_xor(a1, 16, 64);
        a2 += __shfl_xor(a2, 16, 64);
        a3 += __shfl_xor(a3, 16, 64);
        a0 += __shfl_xor(a0, 32, 64);
        a1 += __shfl_xor(a1, 32, 64);
        a2 += __shfl_xor(a2, 32, 64);
        a3 += __shfl_xor(a3, 32, 64);

        if (lane < 16) {
            float4 bb = ((const float4*)bias)[l];
            float4 o;
            o.x = fmaf(a0, di, bb.x);
            o.y = fmaf(a1, di, bb.y);
            o.z = fmaf(a2, di, bb.z);
            o.w = fmaf(a3, di, bb.w);
            ((float4*)out)[(size_t)node * 16 + l] = o;
        }
    }
}

// ---------------- launch ----------------

extern "C" void kernel_launch(void* const* d_in, const int* in_sizes, int n_in,
                              void* d_out, int out_size, void* d_ws, size_t ws_size,
                              hipStream_t stream) {
    const float* x   = (const float*)d_in[0];
    const int*   ei  = (const int*)d_in[1];
    const float* W1  = (const float*)d_in[2];
    const float* b1  = (const float*)d_in[3];
    const float* g1  = (const float*)d_in[4];
    const float* be1 = (const float*)d_in[5];
    const float* W2  = (const float*)d_in[6];
    const float* b2  = (const float*)d_in[7];
    const float* g2  = (const float*)d_in[8];
    const float* be2 = (const float*)d_in[9];
    const float* W3  = (const float*)d_in[10];
    const float* b3  = (const float*)d_in[11];

    int n = in_sizes[0] / 128;
    int E = in_sizes[1] / 2;
    const int* src = ei;
    const int* dst = ei + E;
    int nbuck = (n + BSIZE - 1) / BSIZE;  // 196 for n=100000 (must be <= 256)

    char* p = (char*)d_ws;
    auto alloc = [&](size_t bytes) {
        void* q = (void*)p;
        p += (bytes + 255) & ~(size_t)255;
        return q;
    };
    int*   bfill   = (int*)alloc(256 * 4);
    int*   bbase   = (int*)alloc(256 * 4);
    int*   row_ptr = (int*)alloc((size_t)(n + 1) * 4);
    float* dinv    = (float*)alloc((size_t)n * 4);
    unsigned short* wsw1 = (unsigned short*)alloc(128 * 128 * 2);
    unsigned short* wsw2 = (unsigned short*)alloc(128 * 128 * 2);
    unsigned short* wsw3 = (unsigned short*)alloc(64 * 128 * 2);
    int2*  region  = (int2*)alloc((size_t)nbuck * CAP * 8);
    int*   col     = (int*)alloc((size_t)E * 4);
    unsigned int* bufA = (unsigned int*)alloc((size_t)n * 64 * 4);  // LN out, n x 128 bf16
    unsigned int* bufB = (unsigned int*)alloc((size_t)n * 64 * 4);  // GEMM out (dinv-scaled)

    hipMemsetAsync(bfill, 0, 256 * 4, stream);

    wconv_kernel<<<160, 256, 0, stream>>>(W1, W2, W3, wsw1, wsw2, wsw3);

    int bin_blocks = (E + CHUNK - 1) / CHUNK;
    bin_kernel<<<bin_blocks, 256, 0, stream>>>(src, dst, E, region, bfill);
    bscan_kernel<<<1, 256, 0, stream>>>(bfill, bbase, row_ptr, nbuck, n);
    build_kernel<<<nbuck, 512, 0, stream>>>(region, bfill, bbase, row_ptr, dinv, col, n);

    int gemm_blocks = (n + 127) / 128;
    int agg_blocks = 4096;

    // layer 1
    mfma_gemm_kernel<128, true><<<gemm_blocks, 256, 0, stream>>>(x, wsw1, dinv, bufB, n);
    agg_ln_kernel<<<agg_blocks, 256, 0, stream>>>(bufB, row_ptr, col, dinv, b1, g1, be1, bufA, n);

    // layer 2
    mfma_gemm_kernel<128, false><<<gemm_blocks, 256, 0, stream>>>(bufA, wsw2, dinv, bufB, n);
    agg_ln_kernel<<<agg_blocks, 256, 0, stream>>>(bufB, row_ptr, col, dinv, b2, g2, be2, bufA, n);

    // layer 3
    mfma_gemm_kernel<64, false><<<gemm_blocks, 256, 0, stream>>>(bufA, wsw3, dinv, bufB, n);
    agg64_kernel<<<agg_blocks, 256, 0, stream>>>(bufB, row_ptr, col, dinv, b3, (float*)d_out, n);
}

// Round 8
// 272.070 us; speedup vs baseline: 1.1558x; 1.0189x over previous
//
#include <hip/hip_runtime.h>

using short8 = __attribute__((ext_vector_type(8))) short;
using f32x4  = __attribute__((ext_vector_type(4))) float;

#define BSHIFT 9
#define BSIZE  512     // nodes per bucket
#define CAP    12288   // max edges per bucket region (mean 8192)
#define CHUNK  2048    // edges per bin block

// ---------------- bf16 helpers ----------------

__device__ __forceinline__ float bf_lo(unsigned int v) {
    return __int_as_float((int)(v << 16));
}
__device__ __forceinline__ float bf_hi(unsigned int v) {
    return __int_as_float((int)(v & 0xffff0000u));
}
__device__ __forceinline__ unsigned int f2bf(float f) {
    unsigned int x = __float_as_uint(f);
    x += 0x7fffu + ((x >> 16) & 1u);  // round-to-nearest-even
    return x >> 16;
}
__device__ __forceinline__ unsigned int pack_bf2(float lo, float hi) {
    return f2bf(lo) | (f2bf(hi) << 16);
}

// ---------------- weight pre-convert: fp32 -> bf16, XOR-swizzled [c][k] ----------------

__global__ void wconv_kernel(const float* __restrict__ W1, const float* __restrict__ W2,
                             const float* __restrict__ W3, unsigned short* __restrict__ o1,
                             unsigned short* __restrict__ o2, unsigned short* __restrict__ o3) {
    int i = blockIdx.x * 256 + threadIdx.x;
    const float* W;
    unsigned short* o;
    int ncol, j;
    if (i < 16384)      { W = W1; o = o1; ncol = 128; j = i; }
    else if (i < 32768) { W = W2; o = o2; ncol = 128; j = i - 16384; }
    else if (i < 40960) { W = W3; o = o3; ncol = 64;  j = i - 32768; }
    else return;
    int k = j / ncol, c = j % ncol;
    int byte = (c * 256 + k * 2) ^ ((c & 7) << 4);
    o[byte >> 1] = (unsigned short)f2bf(W[j]);
}

// ---------------- graph prep: bucket binning (packed edges: src | dst_local<<17) ------------

__global__ __launch_bounds__(256) void bin_kernel(
    const int* __restrict__ src, const int* __restrict__ dst, int E,
    int* __restrict__ region, int* __restrict__ bfill) {
    __shared__ int lcnt[256];
    __shared__ int loff[256];
    __shared__ int gbase[256];
    __shared__ int stage[CHUNK];
    __shared__ unsigned short bOf[CHUNK];

    int t = threadIdx.x;
    int e0 = blockIdx.x * CHUNK;
    int cnt = min(CHUNK, E - e0);

    lcnt[t] = 0;
    __syncthreads();

    int s_[8], d_[8], p_[8];
#pragma unroll
    for (int i = 0; i < 8; i++) {
        int e = t + i * 256;
        if (e < cnt) {
            int s = src[e0 + e], d = dst[e0 + e];
            s_[i] = s;
            d_[i] = d;
            p_[i] = atomicAdd(&lcnt[d >> BSHIFT], 1);
        } else {
            d_[i] = -1;
        }
    }
    __syncthreads();

    int v = lcnt[t];
    loff[t] = v;
    __syncthreads();
    for (int off = 1; off < 256; off <<= 1) {
        int u = (t >= off) ? loff[t - off] : 0;
        __syncthreads();
        loff[t] += u;
        __syncthreads();
    }
    int ex = loff[t] - v;
    __syncthreads();
    loff[t] = ex;
    gbase[t] = (v > 0) ? atomicAdd(&bfill[t], v) : 0;
    __syncthreads();

#pragma unroll
    for (int i = 0; i < 8; i++) {
        if (d_[i] >= 0) {
            int b = d_[i] >> BSHIFT;
            int j = loff[b] + p_[i];
            stage[j] = s_[i] | ((d_[i] & (BSIZE - 1)) << 17);
            bOf[j] = (unsigned short)b;
        }
    }
    __syncthreads();

    for (int j = t; j < cnt; j += 256) {
        int b = bOf[j];
        int idx = gbase[b] + (j - loff[b]);
        if (idx < CAP) region[(size_t)b * CAP + idx] = stage[j];
    }
}

// per-bucket: LDS hist -> rbeg/rend/dinv, scatter col into fixed-stride window b*CAP
__global__ __launch_bounds__(512) void build_kernel(
    const int* __restrict__ region, const int* __restrict__ bfill,
    int* __restrict__ rbeg, int* __restrict__ rend, float* __restrict__ dinv,
    int* __restrict__ col, int n) {
    __shared__ int cnt[BSIZE];
    __shared__ int excl[BSIZE];
    __shared__ int fill[BSIZE];
    int b = blockIdx.x;
    int t = threadIdx.x;
    int base = b * BSIZE;
    int ecnt = min(bfill[b], CAP);
    int ebase = b * CAP;
    const int* reg = region + (size_t)b * CAP;

    cnt[t] = 0;
    fill[t] = 0;
    __syncthreads();

    for (int i = t; i < ecnt; i += 512) atomicAdd(&cnt[reg[i] >> 17], 1);
    __syncthreads();

    int v = cnt[t];
    excl[t] = v;
    __syncthreads();
    for (int off = 1; off < 512; off <<= 1) {
        int u = (t >= off) ? excl[t - off] : 0;
        __syncthreads();
        excl[t] += u;
        __syncthreads();
    }
    int ex = excl[t] - v;
    __syncthreads();
    excl[t] = ex;
    __syncthreads();

    int node = base + t;
    if (node < n) {
        rbeg[node] = ebase + ex;
        rend[node] = ebase + ex + v;
        dinv[node] = rsqrtf((float)(v + 1));  // +1 self loop
    }

    for (int i = t; i < ecnt; i += 512) {
        int p = reg[i];
        int li = p >> 17;
        int pos = atomicAdd(&fill[li], 1);
        col[ebase + excl[li] + pos] = p & 0x1FFFF;
    }
}

// ---------------- MFMA dense transform: Y[n x NCOL](bf16) = (X @ W) * dinv[row] -------------

template <int NCOL, bool XF32>
__global__ __launch_bounds__(256) void mfma_gemm_kernel(const void* __restrict__ Xv,
                                                        const unsigned short* __restrict__ Wsw,
                                                        const float* __restrict__ dinv,
                                                        unsigned int* __restrict__ Y, int n) {
    constexpr int CF = NCOL / 16;
    __shared__ unsigned short Wt[(size_t)NCOL * 128];

    int t = threadIdx.x;
    {   // flat copy of pre-swizzled W (NCOL*16 uint4)
        const uint4* Wg = (const uint4*)Wsw;
        uint4* Wl = (uint4*)Wt;
        for (int i = t; i < NCOL * 16; i += 256) Wl[i] = Wg[i];
    }
    __syncthreads();

    int wid = t >> 6, l = t & 63;
    int row0 = blockIdx.x * 128;
    int kq = l >> 4;
    const char* Wb = (const char*)Wt;

    for (int rt = 0; rt < 2; rt++) {
        int xr = row0 + (wid * 2 + rt) * 16 + (l & 15);
        int xrc = min(xr, n - 1);

        f32x4 acc[CF];
#pragma unroll
        for (int cf = 0; cf < CF; cf++) acc[cf] = (f32x4){0.f, 0.f, 0.f, 0.f};

#pragma unroll
        for (int ks = 0; ks < 4; ks++) {
            short8 bq;
            if (XF32) {
                const float* Xf = (const float*)Xv + (size_t)xrc * 128 + ks * 32 + kq * 8;
                float4 x0 = ((const float4*)Xf)[0];
                float4 x1 = ((const float4*)Xf)[1];
                unsigned int p0 = pack_bf2(x0.x, x0.y), p1 = pack_bf2(x0.z, x0.w);
                unsigned int p2 = pack_bf2(x1.x, x1.y), p3 = pack_bf2(x1.z, x1.w);
                uint4 u = make_uint4(p0, p1, p2, p3);
                bq = *(const short8*)&u;
            } else {
                const char* Xb = (const char*)Xv + (size_t)xrc * 256 + ks * 64 + kq * 16;
                bq = *(const short8*)Xb;
            }
#pragma unroll
            for (int cf = 0; cf < CF; cf++) {
                int c = cf * 16 + (l & 15);
                int byte = (c * 256 + ks * 64 + kq * 16) ^ ((c & 7) << 4);
                short8 aq = *(const short8*)(Wb + byte);
                acc[cf] = __builtin_amdgcn_mfma_f32_16x16x32_bf16(aq, bq, acc[cf], 0, 0, 0);
            }
        }

        if (xr < n) {
            float dsc = dinv[xr];
            unsigned int* Yr = Y + (size_t)xr * (NCOL / 2);
#pragma unroll
            for (int cf = 0; cf < CF; cf++) {
                uint2 o = make_uint2(pack_bf2(acc[cf][0] * dsc, acc[cf][1] * dsc),
                                     pack_bf2(acc[cf][2] * dsc, acc[cf][3] * dsc));
                *(uint2*)(Yr + cf * 8 + kq * 2) = o;
            }
        }
    }
}

#define ACC8(v)                 \
    a0 += bf_lo((v).x);         \
    a1 += bf_hi((v).x);         \
    a2 += bf_lo((v).y);         \
    a3 += bf_hi((v).y);         \
    a4 += bf_lo((v).z);         \
    a5 += bf_hi((v).z);         \
    a6 += bf_lo((v).w);         \
    a7 += bf_hi((v).w);

// ---------------- fused aggregate + bias + LayerNorm + ReLU (128 bf16 features) -------------
// Quarter-wave q streams edge e+q; lane l in [0,16) holds features 8l..8l+7 (uint4).

__global__ __launch_bounds__(256) void agg_ln_kernel(
    const unsigned int* __restrict__ tmp, const int* __restrict__ rbeg,
    const int* __restrict__ rend, const int* __restrict__ col,
    const float* __restrict__ dinv, const float* __restrict__ bias,
    const float* __restrict__ gamma, const float* __restrict__ beta,
    unsigned int* __restrict__ out, int n) {
    int wid = threadIdx.x >> 6;
    int lane = threadIdx.x & 63;
    int q = lane >> 4;
    int l = lane & 15;
    int stride = gridDim.x * 4;

    const uint4* T = (const uint4*)tmp;  // row stride 16 uint4 (256B)

    for (int node = blockIdx.x * 4 + wid; node < n; node += stride) {
        float di = dinv[node];
        int beg = __builtin_amdgcn_readfirstlane(rbeg[node]);
        int end = __builtin_amdgcn_readfirstlane(rend[node]);

        float a0 = 0.f, a1 = 0.f, a2 = 0.f, a3 = 0.f;
        float a4 = 0.f, a5 = 0.f, a6 = 0.f, a7 = 0.f;
        int e = beg;
#pragma unroll 2
        for (; e + 3 < end; e += 4) {
            int c0 = col[e], c1 = col[e + 1], c2 = col[e + 2], c3 = col[e + 3];
            int sa = (q & 1) ? c1 : c0;
            int sb = (q & 1) ? c3 : c2;
            int s = (q & 2) ? sb : sa;
            uint4 v = T[(size_t)s * 16 + l];
            ACC8(v)
        }
        int rem = end - e;  // 0..3
        if (q < rem) {
            int s = col[e + q];
            uint4 v = T[(size_t)s * 16 + l];
            ACC8(v)
        }
        if (q == 3) {  // self loop
            uint4 v = T[(size_t)node * 16 + l];
            ACC8(v)
        }
        // combine quarters
        a0 += __shfl_xor(a0, 16, 64); a1 += __shfl_xor(a1, 16, 64);
        a2 += __shfl_xor(a2, 16, 64); a3 += __shfl_xor(a3, 16, 64);
        a4 += __shfl_xor(a4, 16, 64); a5 += __shfl_xor(a5, 16, 64);
        a6 += __shfl_xor(a6, 16, 64); a7 += __shfl_xor(a7, 16, 64);
        a0 += __shfl_xor(a0, 32, 64); a1 += __shfl_xor(a1, 32, 64);
        a2 += __shfl_xor(a2, 32, 64); a3 += __shfl_xor(a3, 32, 64);
        a4 += __shfl_xor(a4, 32, 64); a5 += __shfl_xor(a5, 32, 64);
        a6 += __shfl_xor(a6, 32, 64); a7 += __shfl_xor(a7, 32, 64);

        float4 b0 = ((const float4*)bias)[2 * l];
        float4 b1 = ((const float4*)bias)[2 * l + 1];
        a0 = fmaf(a0, di, b0.x); a1 = fmaf(a1, di, b0.y);
        a2 = fmaf(a2, di, b0.z); a3 = fmaf(a3, di, b0.w);
        a4 = fmaf(a4, di, b1.x); a5 = fmaf(a5, di, b1.y);
        a6 = fmaf(a6, di, b1.z); a7 = fmaf(a7, di, b1.w);

        // LayerNorm across 16 lanes (all quarters hold identical data)
        float s8 = a0 + a1 + a2 + a3 + a4 + a5 + a6 + a7;
#pragma unroll
        for (int m = 1; m < 16; m <<= 1) s8 += __shfl_xor(s8, m, 64);
        float mu = s8 * (1.0f / 128.0f);
        float d0 = a0 - mu, d1 = a1 - mu, d2 = a2 - mu, d3 = a3 - mu;
        float d4 = a4 - mu, d5 = a5 - mu, d6 = a6 - mu, d7 = a7 - mu;
        float vv = d0 * d0 + d1 * d1 + d2 * d2 + d3 * d3 +
                   d4 * d4 + d5 * d5 + d6 * d6 + d7 * d7;
#pragma unroll
        for (int m = 1; m < 16; m <<= 1) vv += __shfl_xor(vv, m, 64);
        float r = rsqrtf(vv * (1.0f / 128.0f) + 1e-5f);

        if (lane < 16) {
            float4 g0 = ((const float4*)gamma)[2 * l];
            float4 g1 = ((const float4*)gamma)[2 * l + 1];
            float4 e0 = ((const float4*)beta)[2 * l];
            float4 e1 = ((const float4*)beta)[2 * l + 1];
            float o0 = fmaxf(fmaf(d0 * r, g0.x, e0.x), 0.f);
            float o1 = fmaxf(fmaf(d1 * r, g0.y, e0.y), 0.f);
            float o2 = fmaxf(fmaf(d2 * r, g0.z, e0.z), 0.f);
            float o3 = fmaxf(fmaf(d3 * r, g0.w, e0.w), 0.f);
            float o4 = fmaxf(fmaf(d4 * r, g1.x, e1.x), 0.f);
            float o5 = fmaxf(fmaf(d5 * r, g1.y, e1.y), 0.f);
            float o6 = fmaxf(fmaf(d6 * r, g1.z, e1.z), 0.f);
            float o7 = fmaxf(fmaf(d7 * r, g1.w, e1.w), 0.f);
            uint4 o = make_uint4(pack_bf2(o0, o1), pack_bf2(o2, o3),
                                 pack_bf2(o4, o5), pack_bf2(o6, o7));
            ((uint4*)out)[(size_t)node * 16 + l] = o;
        }
    }
}

// ---------------- final aggregate + bias (64 bf16 features, no LN) ----------------
// Eighth-wave oc streams edge e+oc; lane l in [0,8) holds features 8l..8l+7 (uint4).

__global__ __launch_bounds__(256) void agg64_kernel(
    const unsigned int* __restrict__ tmp, const int* __restrict__ rbeg,
    const int* __restrict__ rend, const int* __restrict__ col,
    const float* __restrict__ dinv, const float* __restrict__ bias,
    float* __restrict__ out, int n) {
    int wid = threadIdx.x >> 6;
    int lane = threadIdx.x & 63;
    int oc = lane >> 3;
    int l = lane & 7;
    int stride = gridDim.x * 4;

    const uint4* T = (const uint4*)tmp;  // row stride 8 uint4 (128B)

    for (int node = blockIdx.x * 4 + wid; node < n; node += stride) {
        float di = dinv[node];
        int beg = __builtin_amdgcn_readfirstlane(rbeg[node]);
        int end = __builtin_amdgcn_readfirstlane(rend[node]);

        float a0 = 0.f, a1 = 0.f, a2 = 0.f, a3 = 0.f;
        float a4 = 0.f, a5 = 0.f, a6 = 0.f, a7 = 0.f;
        int e = beg;
#pragma unroll 2
        for (; e + 7 < end; e += 8) {
            int c0 = col[e], c1 = col[e + 1], c2 = col[e + 2], c3 = col[e + 3];
            int c4 = col[e + 4], c5 = col[e + 5], c6 = col[e + 6], c7 = col[e + 7];
            int sa = (oc & 1) ? c1 : c0;
            int sb = (oc & 1) ? c3 : c2;
            int sc = (oc & 1) ? c5 : c4;
            int sd = (oc & 1) ? c7 : c6;
            int sab = (oc & 2) ? sb : sa;
            int scd = (oc & 2) ? sd : sc;
            int s = (oc & 4) ? scd : sab;
            uint4 v = T[(size_t)s * 8 + l];
            ACC8(v)
        }
        int rem = end - e;  // 0..7, oc==7 never takes tail
        if (oc < rem) {
            int s = col[e + oc];
            uint4 v = T[(size_t)s * 8 + l];
            ACC8(v)
        }
        if (oc == 7) {  // self loop
            uint4 v = T[(size_t)node * 8 + l];
            ACC8(v)
        }
        a0 += __shfl_xor(a0, 8, 64);  a1 += __shfl_xor(a1, 8, 64);
        a2 += __shfl_xor(a2, 8, 64);  a3 += __shfl_xor(a3, 8, 64);
        a4 += __shfl_xor(a4, 8, 64);  a5 += __shfl_xor(a5, 8, 64);
        a6 += __shfl_xor(a6, 8, 64);  a7 += __shfl_xor(a7, 8, 64);
        a0 += __shfl_xor(a0, 16, 64); a1 += __shfl_xor(a1, 16, 64);
        a2 += __shfl_xor(a2, 16, 64); a3 += __shfl_xor(a3, 16, 64);
        a4 += __shfl_xor(a4, 16, 64); a5 += __shfl_xor(a5, 16, 64);
        a6 += __shfl_xor(a6, 16, 64); a7 += __shfl_xor(a7, 16, 64);
        a0 += __shfl_xor(a0, 32, 64); a1 += __shfl_xor(a1, 32, 64);
        a2 += __shfl_xor(a2, 32, 64); a3 += __shfl_xor(a3, 32, 64);
        a4 += __shfl_xor(a4, 32, 64); a5 += __shfl_xor(a5, 32, 64);
        a6 += __shfl_xor(a6, 32, 64); a7 += __shfl_xor(a7, 32, 64);

        if (lane < 8) {
            float4 b0 = ((const float4*)bias)[2 * l];
            float4 b1 = ((const float4*)bias)[2 * l + 1];
            float4 o0, o1;
            o0.x = fmaf(a0, di, b0.x); o0.y = fmaf(a1, di, b0.y);
            o0.z = fmaf(a2, di, b0.z); o0.w = fmaf(a3, di, b0.w);
            o1.x = fmaf(a4, di, b1.x); o1.y = fmaf(a5, di, b1.y);
            o1.z = fmaf(a6, di, b1.z); o1.w = fmaf(a7, di, b1.w);
            ((float4*)out)[(size_t)node * 16 + 2 * l] = o0;
            ((float4*)out)[(size_t)node * 16 + 2 * l + 1] = o1;
        }
    }
}

// ---------------- launch ----------------

extern "C" void kernel_launch(void* const* d_in, const int* in_sizes, int n_in,
                              void* d_out, int out_size, void* d_ws, size_t ws_size,
                              hipStream_t stream) {
    const float* x   = (const float*)d_in[0];
    const int*   ei  = (const int*)d_in[1];
    const float* W1  = (const float*)d_in[2];
    const float* b1  = (const float*)d_in[3];
    const float* g1  = (const float*)d_in[4];
    const float* be1 = (const float*)d_in[5];
    const float* W2  = (const float*)d_in[6];
    const float* b2  = (const float*)d_in[7];
    const float* g2  = (const float*)d_in[8];
    const float* be2 = (const float*)d_in[9];
    const float* W3  = (const float*)d_in[10];
    const float* b3  = (const float*)d_in[11];

    int n = in_sizes[0] / 128;
    int E = in_sizes[1] / 2;
    const int* src = ei;
    const int* dst = ei + E;
    int nbuck = (n + BSIZE - 1) / BSIZE;  // 196 for n=100000 (n must be < 131072)

    char* p = (char*)d_ws;
    auto alloc = [&](size_t bytes) {
        void* q = (void*)p;
        p += (bytes + 255) & ~(size_t)255;
        return q;
    };
    int*   bfill   = (int*)alloc(256 * 4);
    int*   rbeg    = (int*)alloc((size_t)n * 4);
    int*   rend    = (int*)alloc((size_t)n * 4);
    float* dinv    = (float*)alloc((size_t)n * 4);
    unsigned short* wsw1 = (unsigned short*)alloc(128 * 128 * 2);
    unsigned short* wsw2 = (unsigned short*)alloc(128 * 128 * 2);
    unsigned short* wsw3 = (unsigned short*)alloc(64 * 128 * 2);
    int*   region  = (int*)alloc((size_t)nbuck * CAP * 4);
    int*   col     = (int*)alloc((size_t)nbuck * CAP * 4);
    unsigned int* bufA = (unsigned int*)alloc((size_t)n * 64 * 4);  // LN out, n x 128 bf16
    unsigned int* bufB = (unsigned int*)alloc((size_t)n * 64 * 4);  // GEMM out (dinv-scaled)

    hipMemsetAsync(bfill, 0, 256 * 4, stream);

    wconv_kernel<<<160, 256, 0, stream>>>(W1, W2, W3, wsw1, wsw2, wsw3);

    int bin_blocks = (E + CHUNK - 1) / CHUNK;
    bin_kernel<<<bin_blocks, 256, 0, stream>>>(src, dst, E, region, bfill);
    build_kernel<<<nbuck, 512, 0, stream>>>(region, bfill, rbeg, rend, dinv, col, n);

    int gemm_blocks = (n + 127) / 128;
    int agg_blocks = 4096;

    // layer 1
    mfma_gemm_kernel<128, true><<<gemm_blocks, 256, 0, stream>>>(x, wsw1, dinv, bufB, n);
    agg_ln_kernel<<<agg_blocks, 256, 0, stream>>>(bufB, rbeg, rend, col, dinv, b1, g1, be1, bufA, n);

    // layer 2
    mfma_gemm_kernel<128, false><<<gemm_blocks, 256, 0, stream>>>(bufA, wsw2, dinv, bufB, n);
    agg_ln_kernel<<<agg_blocks, 256, 0, stream>>>(bufB, rbeg, rend, col, dinv, b2, g2, be2, bufA, n);

    // layer 3
    mfma_gemm_kernel<64, false><<<gemm_blocks, 256, 0, stream>>>(bufA, wsw3, dinv, bufB, n);
    agg64_kernel<<<agg_blocks, 256, 0, stream>>>(bufB, rbeg, rend, col, dinv, b3, (float*)d_out, n);
}

// Round 9
// 271.766 us; speedup vs baseline: 1.1571x; 1.0011x over previous
//
#include <hip/hip_runtime.h>

using short8 = __attribute__((ext_vector_type(8))) short;
using f32x4  = __attribute__((ext_vector_type(4))) float;

#define BSHIFT 9
#define BSIZE  512     // nodes per bucket
#define CAP    12288   // max edges per bucket region (mean 8192)
#define CHUNK  2048    // edges per bin block

// ---------------- bf16 helpers ----------------

__device__ __forceinline__ float bf_lo(unsigned int v) {
    return __int_as_float((int)(v << 16));
}
__device__ __forceinline__ float bf_hi(unsigned int v) {
    return __int_as_float((int)(v & 0xffff0000u));
}
__device__ __forceinline__ unsigned int f2bf(float f) {
    unsigned int x = __float_as_uint(f);
    x += 0x7fffu + ((x >> 16) & 1u);  // round-to-nearest-even
    return x >> 16;
}
__device__ __forceinline__ unsigned int pack_bf2(float lo, float hi) {
    return f2bf(lo) | (f2bf(hi) << 16);
}

// ---------------- weight pre-convert: fp32 -> bf16, XOR-swizzled [c][k] ----------------

__global__ void wconv_kernel(const float* __restrict__ W1, const float* __restrict__ W2,
                             const float* __restrict__ W3, unsigned short* __restrict__ o1,
                             unsigned short* __restrict__ o2, unsigned short* __restrict__ o3) {
    int i = blockIdx.x * 256 + threadIdx.x;
    const float* W;
    unsigned short* o;
    int ncol, j;
    if (i < 16384)      { W = W1; o = o1; ncol = 128; j = i; }
    else if (i < 32768) { W = W2; o = o2; ncol = 128; j = i - 16384; }
    else if (i < 40960) { W = W3; o = o3; ncol = 64;  j = i - 32768; }
    else return;
    int k = j / ncol, c = j % ncol;
    int byte = (c * 256 + k * 2) ^ ((c & 7) << 4);
    o[byte >> 1] = (unsigned short)f2bf(W[j]);
}

// ---------------- graph prep: bucket binning (packed edges: src | dst_local<<17) ------------

__global__ __launch_bounds__(256) void bin_kernel(
    const int* __restrict__ src, const int* __restrict__ dst, int E,
    int* __restrict__ region, int* __restrict__ bfill) {
    __shared__ int lcnt[256];
    __shared__ int loff[256];
    __shared__ int gbase[256];
    __shared__ int stage[CHUNK];
    __shared__ unsigned short bOf[CHUNK];

    int t = threadIdx.x;
    int e0 = blockIdx.x * CHUNK;
    int cnt = min(CHUNK, E - e0);

    lcnt[t] = 0;
    __syncthreads();

    int s_[8], d_[8], p_[8];
#pragma unroll
    for (int i = 0; i < 8; i++) {
        int e = t + i * 256;
        if (e < cnt) {
            int s = src[e0 + e], d = dst[e0 + e];
            s_[i] = s;
            d_[i] = d;
            p_[i] = atomicAdd(&lcnt[d >> BSHIFT], 1);
        } else {
            d_[i] = -1;
        }
    }
    __syncthreads();

    int v = lcnt[t];
    loff[t] = v;
    __syncthreads();
    for (int off = 1; off < 256; off <<= 1) {
        int u = (t >= off) ? loff[t - off] : 0;
        __syncthreads();
        loff[t] += u;
        __syncthreads();
    }
    int ex = loff[t] - v;
    __syncthreads();
    loff[t] = ex;
    gbase[t] = (v > 0) ? atomicAdd(&bfill[t], v) : 0;
    __syncthreads();

#pragma unroll
    for (int i = 0; i < 8; i++) {
        if (d_[i] >= 0) {
            int b = d_[i] >> BSHIFT;
            int j = loff[b] + p_[i];
            stage[j] = s_[i] | ((d_[i] & (BSIZE - 1)) << 17);
            bOf[j] = (unsigned short)b;
        }
    }
    __syncthreads();

    for (int j = t; j < cnt; j += 256) {
        int b = bOf[j];
        int idx = gbase[b] + (j - loff[b]);
        if (idx < CAP) region[(size_t)b * CAP + idx] = stage[j];
    }
}

// per-bucket: LDS hist -> rbeg/rend/dinv, scatter col into fixed-stride window b*CAP
__global__ __launch_bounds__(512) void build_kernel(
    const int* __restrict__ region, const int* __restrict__ bfill,
    int* __restrict__ rbeg, int* __restrict__ rend, float* __restrict__ dinv,
    int* __restrict__ col, int n) {
    __shared__ int cnt[BSIZE];
    __shared__ int excl[BSIZE];
    __shared__ int fill[BSIZE];
    int b = blockIdx.x;
    int t = threadIdx.x;
    int base = b * BSIZE;
    int ecnt = min(bfill[b], CAP);
    int ebase = b * CAP;
    const int* reg = region + (size_t)b * CAP;

    cnt[t] = 0;
    fill[t] = 0;
    __syncthreads();

    for (int i = t; i < ecnt; i += 512) atomicAdd(&cnt[reg[i] >> 17], 1);
    __syncthreads();

    int v = cnt[t];
    excl[t] = v;
    __syncthreads();
    for (int off = 1; off < 512; off <<= 1) {
        int u = (t >= off) ? excl[t - off] : 0;
        __syncthreads();
        excl[t] += u;
        __syncthreads();
    }
    int ex = excl[t] - v;
    __syncthreads();
    excl[t] = ex;
    __syncthreads();

    int node = base + t;
    if (node < n) {
        rbeg[node] = ebase + ex;
        rend[node] = ebase + ex + v;
        dinv[node] = rsqrtf((float)(v + 1));  // +1 self loop
    }

    for (int i = t; i < ecnt; i += 512) {
        int p = reg[i];
        int li = p >> 17;
        int pos = atomicAdd(&fill[li], 1);
        col[ebase + excl[li] + pos] = p & 0x1FFFF;
    }
}

// ---------------- MFMA dense transform: Y[n x NCOL](bf16) = (X @ W) * dinv[row] -------------

template <int NCOL, bool XF32>
__global__ __launch_bounds__(256) void mfma_gemm_kernel(const void* __restrict__ Xv,
                                                        const unsigned short* __restrict__ Wsw,
                                                        const float* __restrict__ dinv,
                                                        unsigned int* __restrict__ Y, int n) {
    constexpr int CF = NCOL / 16;
    __shared__ unsigned short Wt[(size_t)NCOL * 128];

    int t = threadIdx.x;
    {   // flat copy of pre-swizzled W (NCOL*16 uint4)
        const uint4* Wg = (const uint4*)Wsw;
        uint4* Wl = (uint4*)Wt;
        for (int i = t; i < NCOL * 16; i += 256) Wl[i] = Wg[i];
    }
    __syncthreads();

    int wid = t >> 6, l = t & 63;
    int row0 = blockIdx.x * 128;
    int kq = l >> 4;
    const char* Wb = (const char*)Wt;

    for (int rt = 0; rt < 2; rt++) {
        int xr = row0 + (wid * 2 + rt) * 16 + (l & 15);
        int xrc = min(xr, n - 1);

        f32x4 acc[CF];
#pragma unroll
        for (int cf = 0; cf < CF; cf++) acc[cf] = (f32x4){0.f, 0.f, 0.f, 0.f};

#pragma unroll
        for (int ks = 0; ks < 4; ks++) {
            short8 bq;
            if (XF32) {
                const float* Xf = (const float*)Xv + (size_t)xrc * 128 + ks * 32 + kq * 8;
                float4 x0 = ((const float4*)Xf)[0];
                float4 x1 = ((const float4*)Xf)[1];
                unsigned int p0 = pack_bf2(x0.x, x0.y), p1 = pack_bf2(x0.z, x0.w);
                unsigned int p2 = pack_bf2(x1.x, x1.y), p3 = pack_bf2(x1.z, x1.w);
                uint4 u = make_uint4(p0, p1, p2, p3);
                bq = *(const short8*)&u;
            } else {
                const char* Xb = (const char*)Xv + (size_t)xrc * 256 + ks * 64 + kq * 16;
                bq = *(const short8*)Xb;
            }
#pragma unroll
            for (int cf = 0; cf < CF; cf++) {
                int c = cf * 16 + (l & 15);
                int byte = (c * 256 + ks * 64 + kq * 16) ^ ((c & 7) << 4);
                short8 aq = *(const short8*)(Wb + byte);
                acc[cf] = __builtin_amdgcn_mfma_f32_16x16x32_bf16(aq, bq, acc[cf], 0, 0, 0);
            }
        }

        if (xr < n) {
            float dsc = dinv[xr];
            unsigned int* Yr = Y + (size_t)xr * (NCOL / 2);
#pragma unroll
            for (int cf = 0; cf < CF; cf++) {
                uint2 o = make_uint2(pack_bf2(acc[cf][0] * dsc, acc[cf][1] * dsc),
                                     pack_bf2(acc[cf][2] * dsc, acc[cf][3] * dsc));
                *(uint2*)(Yr + cf * 8 + kq * 2) = o;
            }
        }
    }
}

#define ACC8(v)                 \
    a0 += bf_lo((v).x);         \
    a1 += bf_hi((v).x);         \
    a2 += bf_lo((v).y);         \
    a3 += bf_hi((v).y);         \
    a4 += bf_lo((v).z);         \
    a5 += bf_hi((v).z);         \
    a6 += bf_lo((v).w);         \
    a7 += bf_hi((v).w);

// ---------------- fused aggregate + bias + LayerNorm + ReLU (128 bf16 features) -------------
// Quarter-wave q streams edge e+q; lane l in [0,16) holds features 8l..8l+7 (uint4).

__global__ __launch_bounds__(256) void agg_ln_kernel(
    const unsigned int* __restrict__ tmp, const int* __restrict__ rbeg,
    const int* __restrict__ rend, const int* __restrict__ col,
    const float* __restrict__ dinv, const float* __restrict__ bias,
    const float* __restrict__ gamma, const float* __restrict__ beta,
    unsigned int* __restrict__ out, int n) {
    int wid = threadIdx.x >> 6;
    int lane = threadIdx.x & 63;
    int q = lane >> 4;
    int l = lane & 15;
    int stride = gridDim.x * 4;

    const uint4* T = (const uint4*)tmp;  // row stride 16 uint4 (256B)

    for (int node = blockIdx.x * 4 + wid; node < n; node += stride) {
        float di = dinv[node];
        int beg = __builtin_amdgcn_readfirstlane(rbeg[node]);
        int end = __builtin_amdgcn_readfirstlane(rend[node]);

        float a0 = 0.f, a1 = 0.f, a2 = 0.f, a3 = 0.f;
        float a4 = 0.f, a5 = 0.f, a6 = 0.f, a7 = 0.f;
        int e = beg;
#pragma unroll 2
        for (; e + 3 < end; e += 4) {
            int c0 = col[e], c1 = col[e + 1], c2 = col[e + 2], c3 = col[e + 3];
            int sa = (q & 1) ? c1 : c0;
            int sb = (q & 1) ? c3 : c2;
            int s = (q & 2) ? sb : sa;
            uint4 v = T[(size_t)s * 16 + l];
            ACC8(v)
        }
        int rem = end - e;  // 0..3
        if (q < rem) {
            int s = col[e + q];
            uint4 v = T[(size_t)s * 16 + l];
            ACC8(v)
        }
        if (q == 3) {  // self loop
            uint4 v = T[(size_t)node * 16 + l];
            ACC8(v)
        }
        // combine quarters
        a0 += __shfl_xor(a0, 16, 64); a1 += __shfl_xor(a1, 16, 64);
        a2 += __shfl_xor(a2, 16, 64); a3 += __shfl_xor(a3, 16, 64);
        a4 += __shfl_xor(a4, 16, 64); a5 += __shfl_xor(a5, 16, 64);
        a6 += __shfl_xor(a6, 16, 64); a7 += __shfl_xor(a7, 16, 64);
        a0 += __shfl_xor(a0, 32, 64); a1 += __shfl_xor(a1, 32, 64);
        a2 += __shfl_xor(a2, 32, 64); a3 += __shfl_xor(a3, 32, 64);
        a4 += __shfl_xor(a4, 32, 64); a5 += __shfl_xor(a5, 32, 64);
        a6 += __shfl_xor(a6, 32, 64); a7 += __shfl_xor(a7, 32, 64);

        float4 b0 = ((const float4*)bias)[2 * l];
        float4 b1 = ((const float4*)bias)[2 * l + 1];
        a0 = fmaf(a0, di, b0.x); a1 = fmaf(a1, di, b0.y);
        a2 = fmaf(a2, di, b0.z); a3 = fmaf(a3, di, b0.w);
        a4 = fmaf(a4, di, b1.x); a5 = fmaf(a5, di, b1.y);
        a6 = fmaf(a6, di, b1.z); a7 = fmaf(a7, di, b1.w);

        // LayerNorm across 16 lanes (all quarters hold identical data)
        float s8 = a0 + a1 + a2 + a3 + a4 + a5 + a6 + a7;
#pragma unroll
        for (int m = 1; m < 16; m <<= 1) s8 += __shfl_xor(s8, m, 64);
        float mu = s8 * (1.0f / 128.0f);
        float d0 = a0 - mu, d1 = a1 - mu, d2 = a2 - mu, d3 = a3 - mu;
        float d4 = a4 - mu, d5 = a5 - mu, d6 = a6 - mu, d7 = a7 - mu;
        float vv = d0 * d0 + d1 * d1 + d2 * d2 + d3 * d3 +
                   d4 * d4 + d5 * d5 + d6 * d6 + d7 * d7;
#pragma unroll
        for (int m = 1; m < 16; m <<= 1) vv += __shfl_xor(vv, m, 64);
        float r = rsqrtf(vv * (1.0f / 128.0f) + 1e-5f);

        if (lane < 16) {
            float4 g0 = ((const float4*)gamma)[2 * l];
            float4 g1 = ((const float4*)gamma)[2 * l + 1];
            float4 e0 = ((const float4*)beta)[2 * l];
            float4 e1 = ((const float4*)beta)[2 * l + 1];
            float o0 = fmaxf(fmaf(d0 * r, g0.x, e0.x), 0.f);
            float o1 = fmaxf(fmaf(d1 * r, g0.y, e0.y), 0.f);
            float o2 = fmaxf(fmaf(d2 * r, g0.z, e0.z), 0.f);
            float o3 = fmaxf(fmaf(d3 * r, g0.w, e0.w), 0.f);
            float o4 = fmaxf(fmaf(d4 * r, g1.x, e1.x), 0.f);
            float o5 = fmaxf(fmaf(d5 * r, g1.y, e1.y), 0.f);
            float o6 = fmaxf(fmaf(d6 * r, g1.z, e1.z), 0.f);
            float o7 = fmaxf(fmaf(d7 * r, g1.w, e1.w), 0.f);
            uint4 o = make_uint4(pack_bf2(o0, o1), pack_bf2(o2, o3),
                                 pack_bf2(o4, o5), pack_bf2(o6, o7));
            ((uint4*)out)[(size_t)node * 16 + l] = o;
        }
    }
}

// ---------------- final aggregate + bias (64 bf16 features, no LN) ----------------
// Eighth-wave oc streams edge e+oc; lane l in [0,8) holds features 8l..8l+7 (uint4).

__global__ __launch_bounds__(256) void agg64_kernel(
    const unsigned int* __restrict__ tmp, const int* __restrict__ rbeg,
    const int* __restrict__ rend, const int* __restrict__ col,
    const float* __restrict__ dinv, const float* __restrict__ bias,
    float* __restrict__ out, int n) {
    int wid = threadIdx.x >> 6;
    int lane = threadIdx.x & 63;
    int oc = lane >> 3;
    int l = lane & 7;
    int stride = gridDim.x * 4;

    const uint4* T = (const uint4*)tmp;  // row stride 8 uint4 (128B)

    for (int node = blockIdx.x * 4 + wid; node < n; node += stride) {
        float di = dinv[node];
        int beg = __builtin_amdgcn_readfirstlane(rbeg[node]);
        int end = __builtin_amdgcn_readfirstlane(rend[node]);

        float a0 = 0.f, a1 = 0.f, a2 = 0.f, a3 = 0.f;
        float a4 = 0.f, a5 = 0.f, a6 = 0.f, a7 = 0.f;
        int e = beg;
#pragma unroll 2
        for (; e + 7 < end; e += 8) {
            int c0 = col[e], c1 = col[e + 1], c2 = col[e + 2], c3 = col[e + 3];
            int c4 = col[e + 4], c5 = col[e + 5], c6 = col[e + 6], c7 = col[e + 7];
            int sa = (oc & 1) ? c1 : c0;
            int sb = (oc & 1) ? c3 : c2;
            int sc = (oc & 1) ? c5 : c4;
            int sd = (oc & 1) ? c7 : c6;
            int sab = (oc & 2) ? sb : sa;
            int scd = (oc & 2) ? sd : sc;
            int s = (oc & 4) ? scd : sab;
            uint4 v = T[(size_t)s * 8 + l];
            ACC8(v)
        }
        int rem = end - e;  // 0..7, oc==7 never takes tail
        if (oc < rem) {
            int s = col[e + oc];
            uint4 v = T[(size_t)s * 8 + l];
            ACC8(v)
        }
        if (oc == 7) {  // self loop
            uint4 v = T[(size_t)node * 8 + l];
            ACC8(v)
        }
        a0 += __shfl_xor(a0, 8, 64);  a1 += __shfl_xor(a1, 8, 64);
        a2 += __shfl_xor(a2, 8, 64);  a3 += __shfl_xor(a3, 8, 64);
        a4 += __shfl_xor(a4, 8, 64);  a5 += __shfl_xor(a5, 8, 64);
        a6 += __shfl_xor(a6, 8, 64);  a7 += __shfl_xor(a7, 8, 64);
        a0 += __shfl_xor(a0, 16, 64); a1 += __shfl_xor(a1, 16, 64);
        a2 += __shfl_xor(a2, 16, 64); a3 += __shfl_xor(a3, 16, 64);
        a4 += __shfl_xor(a4, 16, 64); a5 += __shfl_xor(a5, 16, 64);
        a6 += __shfl_xor(a6, 16, 64); a7 += __shfl_xor(a7, 16, 64);
        a0 += __shfl_xor(a0, 32, 64); a1 += __shfl_xor(a1, 32, 64);
        a2 += __shfl_xor(a2, 32, 64); a3 += __shfl_xor(a3, 32, 64);
        a4 += __shfl_xor(a4, 32, 64); a5 += __shfl_xor(a5, 32, 64);
        a6 += __shfl_xor(a6, 32, 64); a7 += __shfl_xor(a7, 32, 64);

        if (lane < 8) {
            float4 b0 = ((const float4*)bias)[2 * l];
            float4 b1 = ((const float4*)bias)[2 * l + 1];
            float4 o0, o1;
            o0.x = fmaf(a0, di, b0.x); o0.y = fmaf(a1, di, b0.y);
            o0.z = fmaf(a2, di, b0.z); o0.w = fmaf(a3, di, b0.w);
            o1.x = fmaf(a4, di, b1.x); o1.y = fmaf(a5, di, b1.y);
            o1.z = fmaf(a6, di, b1.z); o1.w = fmaf(a7, di, b1.w);
            ((float4*)out)[(size_t)node * 16 + 2 * l] = o0;
            ((float4*)out)[(size_t)node * 16 + 2 * l + 1] = o1;
        }
    }
}

// ---------------- launch ----------------

extern "C" void kernel_launch(void* const* d_in, const int* in_sizes, int n_in,
                              void* d_out, int out_size, void* d_ws, size_t ws_size,
                              hipStream_t stream) {
    const float* x   = (const float*)d_in[0];
    const int*   ei  = (const int*)d_in[1];
    const float* W1  = (const float*)d_in[2];
    const float* b1  = (const float*)d_in[3];
    const float* g1  = (const float*)d_in[4];
    const float* be1 = (const float*)d_in[5];
    const float* W2  = (const float*)d_in[6];
    const float* b2  = (const float*)d_in[7];
    const float* g2  = (const float*)d_in[8];
    const float* be2 = (const float*)d_in[9];
    const float* W3  = (const float*)d_in[10];
    const float* b3  = (const float*)d_in[11];

    int n = in_sizes[0] / 128;
    int E = in_sizes[1] / 2;
    const int* src = ei;
    const int* dst = ei + E;
    int nbuck = (n + BSIZE - 1) / BSIZE;  // 196 for n=100000 (n must be < 131072)

    char* p = (char*)d_ws;
    auto alloc = [&](size_t bytes) {
        void* q = (void*)p;
        p += (bytes + 255) & ~(size_t)255;
        return q;
    };
    int*   bfill   = (int*)alloc(256 * 4);
    int*   rbeg    = (int*)alloc((size_t)n * 4);
    int*   rend    = (int*)alloc((size_t)n * 4);
    float* dinv    = (float*)alloc((size_t)n * 4);
    unsigned short* wsw1 = (unsigned short*)alloc(128 * 128 * 2);
    unsigned short* wsw2 = (unsigned short*)alloc(128 * 128 * 2);
    unsigned short* wsw3 = (unsigned short*)alloc(64 * 128 * 2);
    int*   region  = (int*)alloc((size_t)nbuck * CAP * 4);
    int*   col     = (int*)alloc((size_t)nbuck * CAP * 4);
    unsigned int* bufA = (unsigned int*)alloc((size_t)n * 64 * 4);  // LN out, n x 128 bf16
    unsigned int* bufB = (unsigned int*)alloc((size_t)n * 64 * 4);  // GEMM out (dinv-scaled)

    hipMemsetAsync(bfill, 0, 256 * 4, stream);

    wconv_kernel<<<160, 256, 0, stream>>>(W1, W2, W3, wsw1, wsw2, wsw3);

    int bin_blocks = (E + CHUNK - 1) / CHUNK;
    bin_kernel<<<bin_blocks, 256, 0, stream>>>(src, dst, E, region, bfill);
    build_kernel<<<nbuck, 512, 0, stream>>>(region, bfill, rbeg, rend, dinv, col, n);

    int gemm_blocks = (n + 127) / 128;
    int agg_blocks = 4096;

    // layer 1
    mfma_gemm_kernel<128, true><<<gemm_blocks, 256, 0, stream>>>(x, wsw1, dinv, bufB, n);
    agg_ln_kernel<<<agg_blocks, 256, 0, stream>>>(bufB, rbeg, rend, col, dinv, b1, g1, be1, bufA, n);

    // layer 2
    mfma_gemm_kernel<128, false><<<gemm_blocks, 256, 0, stream>>>(bufA, wsw2, dinv, bufB, n);
    agg_ln_kernel<<<agg_blocks, 256, 0, stream>>>(bufB, rbeg, rend, col, dinv, b2, g2, be2, bufA, n);

    // layer 3
    mfma_gemm_kernel<64, false><<<gemm_blocks, 256, 0, stream>>>(bufA, wsw3, dinv, bufB, n);
    agg64_kernel<<<agg_blocks, 256, 0, stream>>>(bufB, rbeg, rend, col, dinv, b3, (float*)d_out, n);
}

// Round 10
// 265.394 us; speedup vs baseline: 1.1849x; 1.0240x over previous
//
#include <hip/hip_runtime.h>

using short8 = __attribute__((ext_vector_type(8))) short;
using f32x4  = __attribute__((ext_vector_type(4))) float;

#define BSHIFT 9
#define BSIZE  512     // nodes per bucket
#define CAP    12288   // max edges per bucket region (mean 8192)
#define CHUNK  2048    // edges per bin block

// ---------------- bf16 helpers ----------------

__device__ __forceinline__ float bf_lo(unsigned int v) {
    return __int_as_float((int)(v << 16));
}
__device__ __forceinline__ float bf_hi(unsigned int v) {
    return __int_as_float((int)(v & 0xffff0000u));
}
__device__ __forceinline__ unsigned int f2bf(float f) {
    unsigned int x = __float_as_uint(f);
    x += 0x7fffu + ((x >> 16) & 1u);  // round-to-nearest-even
    return x >> 16;
}
__device__ __forceinline__ unsigned int pack_bf2(float lo, float hi) {
    return f2bf(lo) | (f2bf(hi) << 16);
}

// ---------------- setup: W fp32 -> bf16 XOR-swizzled [c][k]; block 160 zeroes bfill --------

__global__ void wconv_kernel(const float* __restrict__ W1, const float* __restrict__ W2,
                             const float* __restrict__ W3, unsigned short* __restrict__ o1,
                             unsigned short* __restrict__ o2, unsigned short* __restrict__ o3,
                             int* __restrict__ bfill) {
    if (blockIdx.x == 160) {
        bfill[threadIdx.x] = 0;
        return;
    }
    int i = blockIdx.x * 256 + threadIdx.x;
    const float* W;
    unsigned short* o;
    int ncol, j;
    if (i < 16384)      { W = W1; o = o1; ncol = 128; j = i; }
    else if (i < 32768) { W = W2; o = o2; ncol = 128; j = i - 16384; }
    else if (i < 40960) { W = W3; o = o3; ncol = 64;  j = i - 32768; }
    else return;
    int k = j / ncol, c = j % ncol;
    int byte = (c * 256 + k * 2) ^ ((c & 7) << 4);
    o[byte >> 1] = (unsigned short)f2bf(W[j]);
}

// ---------------- graph prep: bucket binning (packed edges: src | dst_local<<17) ------------

__global__ __launch_bounds__(256) void bin_kernel(
    const int* __restrict__ src, const int* __restrict__ dst, int E,
    int* __restrict__ region, int* __restrict__ bfill) {
    __shared__ int lcnt[256];
    __shared__ int loff[256];
    __shared__ int gbase[256];
    __shared__ int stage[CHUNK];
    __shared__ unsigned short bOf[CHUNK];

    int t = threadIdx.x;
    int e0 = blockIdx.x * CHUNK;
    int cnt = min(CHUNK, E - e0);

    lcnt[t] = 0;
    __syncthreads();

    int s_[8], d_[8], p_[8];
#pragma unroll
    for (int i = 0; i < 8; i++) {
        int e = t + i * 256;
        if (e < cnt) {
            int s = src[e0 + e], d = dst[e0 + e];
            s_[i] = s;
            d_[i] = d;
            p_[i] = atomicAdd(&lcnt[d >> BSHIFT], 1);
        } else {
            d_[i] = -1;
        }
    }
    __syncthreads();

    int v = lcnt[t];
    loff[t] = v;
    __syncthreads();
    for (int off = 1; off < 256; off <<= 1) {
        int u = (t >= off) ? loff[t - off] : 0;
        __syncthreads();
        loff[t] += u;
        __syncthreads();
    }
    int ex = loff[t] - v;
    __syncthreads();
    loff[t] = ex;
    gbase[t] = (v > 0) ? atomicAdd(&bfill[t], v) : 0;
    __syncthreads();

#pragma unroll
    for (int i = 0; i < 8; i++) {
        if (d_[i] >= 0) {
            int b = d_[i] >> BSHIFT;
            int j = loff[b] + p_[i];
            stage[j] = s_[i] | ((d_[i] & (BSIZE - 1)) << 17);
            bOf[j] = (unsigned short)b;
        }
    }
    __syncthreads();

    for (int j = t; j < cnt; j += 256) {
        int b = bOf[j];
        int idx = gbase[b] + (j - loff[b]);
        if (idx < CAP) region[(size_t)b * CAP + idx] = stage[j];
    }
}

// per-bucket: LDS hist -> rinfo(beg,end)/dinv, scatter col into fixed-stride window b*CAP
__global__ __launch_bounds__(512) void build_kernel(
    const int* __restrict__ region, const int* __restrict__ bfill,
    int2* __restrict__ rinfo, float* __restrict__ dinv,
    int* __restrict__ col, int n) {
    __shared__ int cnt[BSIZE];
    __shared__ int excl[BSIZE];
    __shared__ int fill[BSIZE];
    int b = blockIdx.x;
    int t = threadIdx.x;
    int base = b * BSIZE;
    int ecnt = min(bfill[b], CAP);
    int ebase = b * CAP;
    const int* reg = region + (size_t)b * CAP;

    cnt[t] = 0;
    fill[t] = 0;
    __syncthreads();

    for (int i = t; i < ecnt; i += 512) atomicAdd(&cnt[reg[i] >> 17], 1);
    __syncthreads();

    int v = cnt[t];
    excl[t] = v;
    __syncthreads();
    for (int off = 1; off < 512; off <<= 1) {
        int u = (t >= off) ? excl[t - off] : 0;
        __syncthreads();
        excl[t] += u;
        __syncthreads();
    }
    int ex = excl[t] - v;
    __syncthreads();
    excl[t] = ex;
    __syncthreads();

    int node = base + t;
    if (node < n) {
        rinfo[node] = make_int2(ebase + ex, ebase + ex + v);
        dinv[node] = rsqrtf((float)(v + 1));  // +1 self loop
    }

    for (int i = t; i < ecnt; i += 512) {
        int p = reg[i];
        int li = p >> 17;
        int pos = atomicAdd(&fill[li], 1);
        col[ebase + excl[li] + pos] = p & 0x1FFFF;
    }
}

// ---------------- MFMA dense transform: Y[n x NCOL](bf16) = (X @ W) * dinv[row] -------------

template <int NCOL, bool XF32>
__global__ __launch_bounds__(256) void mfma_gemm_kernel(const void* __restrict__ Xv,
                                                        const unsigned short* __restrict__ Wsw,
                                                        const float* __restrict__ dinv,
                                                        unsigned int* __restrict__ Y, int n) {
    constexpr int CF = NCOL / 16;
    __shared__ unsigned short Wt[(size_t)NCOL * 128];

    int t = threadIdx.x;
    {   // flat copy of pre-swizzled W (NCOL*16 uint4)
        const uint4* Wg = (const uint4*)Wsw;
        uint4* Wl = (uint4*)Wt;
        for (int i = t; i < NCOL * 16; i += 256) Wl[i] = Wg[i];
    }
    __syncthreads();

    int wid = t >> 6, l = t & 63;
    int row0 = blockIdx.x * 128;
    int kq = l >> 4;
    const char* Wb = (const char*)Wt;

    for (int rt = 0; rt < 2; rt++) {
        int xr = row0 + (wid * 2 + rt) * 16 + (l & 15);
        int xrc = min(xr, n - 1);

        f32x4 acc[CF];
#pragma unroll
        for (int cf = 0; cf < CF; cf++) acc[cf] = (f32x4){0.f, 0.f, 0.f, 0.f};

#pragma unroll
        for (int ks = 0; ks < 4; ks++) {
            short8 bq;
            if (XF32) {
                const float* Xf = (const float*)Xv + (size_t)xrc * 128 + ks * 32 + kq * 8;
                float4 x0 = ((const float4*)Xf)[0];
                float4 x1 = ((const float4*)Xf)[1];
                unsigned int p0 = pack_bf2(x0.x, x0.y), p1 = pack_bf2(x0.z, x0.w);
                unsigned int p2 = pack_bf2(x1.x, x1.y), p3 = pack_bf2(x1.z, x1.w);
                uint4 u = make_uint4(p0, p1, p2, p3);
                bq = *(const short8*)&u;
            } else {
                const char* Xb = (const char*)Xv + (size_t)xrc * 256 + ks * 64 + kq * 16;
                bq = *(const short8*)Xb;
            }
#pragma unroll
            for (int cf = 0; cf < CF; cf++) {
                int c = cf * 16 + (l & 15);
                int byte = (c * 256 + ks * 64 + kq * 16) ^ ((c & 7) << 4);
                short8 aq = *(const short8*)(Wb + byte);
                acc[cf] = __builtin_amdgcn_mfma_f32_16x16x32_bf16(aq, bq, acc[cf], 0, 0, 0);
            }
        }

        if (xr < n) {
            float dsc = dinv[xr];
            unsigned int* Yr = Y + (size_t)xr * (NCOL / 2);
#pragma unroll
            for (int cf = 0; cf < CF; cf++) {
                uint2 o = make_uint2(pack_bf2(acc[cf][0] * dsc, acc[cf][1] * dsc),
                                     pack_bf2(acc[cf][2] * dsc, acc[cf][3] * dsc));
                *(uint2*)(Yr + cf * 8 + kq * 2) = o;
            }
        }
    }
}

#define ACC8(v)                 \
    a0 += bf_lo((v).x);         \
    a1 += bf_hi((v).x);         \
    a2 += bf_lo((v).y);         \
    a3 += bf_hi((v).y);         \
    a4 += bf_lo((v).z);         \
    a5 += bf_hi((v).z);         \
    a6 += bf_lo((v).w);         \
    a7 += bf_hi((v).w);

// ---------------- fused aggregate + bias + LayerNorm + ReLU (128 bf16 features) -------------
// Quarter-wave q; lane l in [0,16) holds features 8l..8l+7 (uint4).
// Main loop streams 8 edges per iteration: quarter q handles e+q and e+q+4
// (2 independent 256B gathers in flight per lane; x2 with unroll).

__global__ __launch_bounds__(256) void agg_ln_kernel(
    const unsigned int* __restrict__ tmp, const int2* __restrict__ rinfo,
    const int* __restrict__ col, const float* __restrict__ dinv,
    const float* __restrict__ bias, const float* __restrict__ gamma,
    const float* __restrict__ beta, unsigned int* __restrict__ out, int n) {
    int wid = threadIdx.x >> 6;
    int lane = threadIdx.x & 63;
    int q = lane >> 4;
    int l = lane & 15;
    int stride = gridDim.x * 4;

    const uint4* T = (const uint4*)tmp;  // row stride 16 uint4 (256B)

    for (int node = blockIdx.x * 4 + wid; node < n; node += stride) {
        float di = dinv[node];
        int2 be = rinfo[node];
        int beg = __builtin_amdgcn_readfirstlane(be.x);
        int end = __builtin_amdgcn_readfirstlane(be.y);

        float a0 = 0.f, a1 = 0.f, a2 = 0.f, a3 = 0.f;
        float a4 = 0.f, a5 = 0.f, a6 = 0.f, a7 = 0.f;
        int e = beg;
#pragma unroll 2
        for (; e + 7 < end; e += 8) {
            int c0 = col[e], c1 = col[e + 1], c2 = col[e + 2], c3 = col[e + 3];
            int c4 = col[e + 4], c5 = col[e + 5], c6 = col[e + 6], c7 = col[e + 7];
            int sa = (q & 1) ? c1 : c0;
            int sb = (q & 1) ? c3 : c2;
            int s1 = (q & 2) ? sb : sa;
            int sc = (q & 1) ? c5 : c4;
            int sd = (q & 1) ? c7 : c6;
            int s2 = (q & 2) ? sd : sc;
            uint4 v1 = T[(size_t)s1 * 16 + l];
            uint4 v2 = T[(size_t)s2 * 16 + l];
            ACC8(v1)
            ACC8(v2)
        }
        if (e + 3 < end) {
            int c0 = col[e], c1 = col[e + 1], c2 = col[e + 2], c3 = col[e + 3];
            int sa = (q & 1) ? c1 : c0;
            int sb = (q & 1) ? c3 : c2;
            int s = (q & 2) ? sb : sa;
            uint4 v = T[(size_t)s * 16 + l];
            ACC8(v)
            e += 4;
        }
        int rem = end - e;  // 0..3
        if (q < rem) {
            int s = col[e + q];
            uint4 v = T[(size_t)s * 16 + l];
            ACC8(v)
        }
        if (q == 3) {  // self loop
            uint4 v = T[(size_t)node * 16 + l];
            ACC8(v)
        }
        // combine quarters
        a0 += __shfl_xor(a0, 16, 64); a1 += __shfl_xor(a1, 16, 64);
        a2 += __shfl_xor(a2, 16, 64); a3 += __shfl_xor(a3, 16, 64);
        a4 += __shfl_xor(a4, 16, 64); a5 += __shfl_xor(a5, 16, 64);
        a6 += __shfl_xor(a6, 16, 64); a7 += __shfl_xor(a7, 16, 64);
        a0 += __shfl_xor(a0, 32, 64); a1 += __shfl_xor(a1, 32, 64);
        a2 += __shfl_xor(a2, 32, 64); a3 += __shfl_xor(a3, 32, 64);
        a4 += __shfl_xor(a4, 32, 64); a5 += __shfl_xor(a5, 32, 64);
        a6 += __shfl_xor(a6, 32, 64); a7 += __shfl_xor(a7, 32, 64);

        float4 b0 = ((const float4*)bias)[2 * l];
        float4 b1 = ((const float4*)bias)[2 * l + 1];
        a0 = fmaf(a0, di, b0.x); a1 = fmaf(a1, di, b0.y);
        a2 = fmaf(a2, di, b0.z); a3 = fmaf(a3, di, b0.w);
        a4 = fmaf(a4, di, b1.x); a5 = fmaf(a5, di, b1.y);
        a6 = fmaf(a6, di, b1.z); a7 = fmaf(a7, di, b1.w);

        // LayerNorm across 16 lanes (all quarters hold identical data)
        float s8 = a0 + a1 + a2 + a3 + a4 + a5 + a6 + a7;
#pragma unroll
        for (int m = 1; m < 16; m <<= 1) s8 += __shfl_xor(s8, m, 64);
        float mu = s8 * (1.0f / 128.0f);
        float d0 = a0 - mu, d1 = a1 - mu, d2 = a2 - mu, d3 = a3 - mu;
        float d4 = a4 - mu, d5 = a5 - mu, d6 = a6 - mu, d7 = a7 - mu;
        float vv = d0 * d0 + d1 * d1 + d2 * d2 + d3 * d3 +
                   d4 * d4 + d5 * d5 + d6 * d6 + d7 * d7;
#pragma unroll
        for (int m = 1; m < 16; m <<= 1) vv += __shfl_xor(vv, m, 64);
        float r = rsqrtf(vv * (1.0f / 128.0f) + 1e-5f);

        if (lane < 16) {
            float4 g0 = ((const float4*)gamma)[2 * l];
            float4 g1 = ((const float4*)gamma)[2 * l + 1];
            float4 e0 = ((const float4*)beta)[2 * l];
            float4 e1 = ((const float4*)beta)[2 * l + 1];
            float o0 = fmaxf(fmaf(d0 * r, g0.x, e0.x), 0.f);
            float o1 = fmaxf(fmaf(d1 * r, g0.y, e0.y), 0.f);
            float o2 = fmaxf(fmaf(d2 * r, g0.z, e0.z), 0.f);
            float o3 = fmaxf(fmaf(d3 * r, g0.w, e0.w), 0.f);
            float o4 = fmaxf(fmaf(d4 * r, g1.x, e1.x), 0.f);
            float o5 = fmaxf(fmaf(d5 * r, g1.y, e1.y), 0.f);
            float o6 = fmaxf(fmaf(d6 * r, g1.z, e1.z), 0.f);
            float o7 = fmaxf(fmaf(d7 * r, g1.w, e1.w), 0.f);
            uint4 o = make_uint4(pack_bf2(o0, o1), pack_bf2(o2, o3),
                                 pack_bf2(o4, o5), pack_bf2(o6, o7));
            ((uint4*)out)[(size_t)node * 16 + l] = o;
        }
    }
}

// ---------------- final aggregate + bias (64 bf16 features, no LN) ----------------
// Eighth-wave oc streams edge e+oc; lane l in [0,8) holds features 8l..8l+7 (uint4).

__global__ __launch_bounds__(256) void agg64_kernel(
    const unsigned int* __restrict__ tmp, const int2* __restrict__ rinfo,
    const int* __restrict__ col, const float* __restrict__ dinv,
    const float* __restrict__ bias, float* __restrict__ out, int n) {
    int wid = threadIdx.x >> 6;
    int lane = threadIdx.x & 63;
    int oc = lane >> 3;
    int l = lane & 7;
    int stride = gridDim.x * 4;

    const uint4* T = (const uint4*)tmp;  // row stride 8 uint4 (128B)

    for (int node = blockIdx.x * 4 + wid; node < n; node += stride) {
        float di = dinv[node];
        int2 be = rinfo[node];
        int beg = __builtin_amdgcn_readfirstlane(be.x);
        int end = __builtin_amdgcn_readfirstlane(be.y);

        float a0 = 0.f, a1 = 0.f, a2 = 0.f, a3 = 0.f;
        float a4 = 0.f, a5 = 0.f, a6 = 0.f, a7 = 0.f;
        int e = beg;
#pragma unroll 2
        for (; e + 7 < end; e += 8) {
            int c0 = col[e], c1 = col[e + 1], c2 = col[e + 2], c3 = col[e + 3];
            int c4 = col[e + 4], c5 = col[e + 5], c6 = col[e + 6], c7 = col[e + 7];
            int sa = (oc & 1) ? c1 : c0;
            int sb = (oc & 1) ? c3 : c2;
            int sc = (oc & 1) ? c5 : c4;
            int sd = (oc & 1) ? c7 : c6;
            int sab = (oc & 2) ? sb : sa;
            int scd = (oc & 2) ? sd : sc;
            int s = (oc & 4) ? scd : sab;
            uint4 v = T[(size_t)s * 8 + l];
            ACC8(v)
        }
        int rem = end - e;  // 0..7, oc==7 never takes tail
        if (oc < rem) {
            int s = col[e + oc];
            uint4 v = T[(size_t)s * 8 + l];
            ACC8(v)
        }
        if (oc == 7) {  // self loop
            uint4 v = T[(size_t)node * 8 + l];
            ACC8(v)
        }
        a0 += __shfl_xor(a0, 8, 64);  a1 += __shfl_xor(a1, 8, 64);
        a2 += __shfl_xor(a2, 8, 64);  a3 += __shfl_xor(a3, 8, 64);
        a4 += __shfl_xor(a4, 8, 64);  a5 += __shfl_xor(a5, 8, 64);
        a6 += __shfl_xor(a6, 8, 64);  a7 += __shfl_xor(a7, 8, 64);
        a0 += __shfl_xor(a0, 16, 64); a1 += __shfl_xor(a1, 16, 64);
        a2 += __shfl_xor(a2, 16, 64); a3 += __shfl_xor(a3, 16, 64);
        a4 += __shfl_xor(a4, 16, 64); a5 += __shfl_xor(a5, 16, 64);
        a6 += __shfl_xor(a6, 16, 64); a7 += __shfl_xor(a7, 16, 64);
        a0 += __shfl_xor(a0, 32, 64); a1 += __shfl_xor(a1, 32, 64);
        a2 += __shfl_xor(a2, 32, 64); a3 += __shfl_xor(a3, 32, 64);
        a4 += __shfl_xor(a4, 32, 64); a5 += __shfl_xor(a5, 32, 64);
        a6 += __shfl_xor(a6, 32, 64); a7 += __shfl_xor(a7, 32, 64);

        if (lane < 8) {
            float4 b0 = ((const float4*)bias)[2 * l];
            float4 b1 = ((const float4*)bias)[2 * l + 1];
            float4 o0, o1;
            o0.x = fmaf(a0, di, b0.x); o0.y = fmaf(a1, di, b0.y);
            o0.z = fmaf(a2, di, b0.z); o0.w = fmaf(a3, di, b0.w);
            o1.x = fmaf(a4, di, b1.x); o1.y = fmaf(a5, di, b1.y);
            o1.z = fmaf(a6, di, b1.z); o1.w = fmaf(a7, di, b1.w);
            ((float4*)out)[(size_t)node * 16 + 2 * l] = o0;
            ((float4*)out)[(size_t)node * 16 + 2 * l + 1] = o1;
        }
    }
}

// ---------------- launch ----------------

extern "C" void kernel_launch(void* const* d_in, const int* in_sizes, int n_in,
                              void* d_out, int out_size, void* d_ws, size_t ws_size,
                              hipStream_t stream) {
    const float* x   = (const float*)d_in[0];
    const int*   ei  = (const int*)d_in[1];
    const float* W1  = (const float*)d_in[2];
    const float* b1  = (const float*)d_in[3];
    const float* g1  = (const float*)d_in[4];
    const float* be1 = (const float*)d_in[5];
    const float* W2  = (const float*)d_in[6];
    const float* b2  = (const float*)d_in[7];
    const float* g2  = (const float*)d_in[8];
    const float* be2 = (const float*)d_in[9];
    const float* W3  = (const float*)d_in[10];
    const float* b3  = (const float*)d_in[11];

    int n = in_sizes[0] / 128;
    int E = in_sizes[1] / 2;
    const int* src = ei;
    const int* dst = ei + E;
    int nbuck = (n + BSIZE - 1) / BSIZE;  // 196 for n=100000 (n must be < 131072)

    char* p = (char*)d_ws;
    auto alloc = [&](size_t bytes) {
        void* q = (void*)p;
        p += (bytes + 255) & ~(size_t)255;
        return q;
    };
    int*   bfill   = (int*)alloc(256 * 4);
    int2*  rinfo   = (int2*)alloc((size_t)n * 8);
    float* dinv    = (float*)alloc((size_t)n * 4);
    unsigned short* wsw1 = (unsigned short*)alloc(128 * 128 * 2);
    unsigned short* wsw2 = (unsigned short*)alloc(128 * 128 * 2);
    unsigned short* wsw3 = (unsigned short*)alloc(64 * 128 * 2);
    int*   region  = (int*)alloc((size_t)nbuck * CAP * 4);
    int*   col     = (int*)alloc((size_t)nbuck * CAP * 4);
    unsigned int* bufA = (unsigned int*)alloc((size_t)n * 64 * 4);  // LN out, n x 128 bf16
    unsigned int* bufB = (unsigned int*)alloc((size_t)n * 64 * 4);  // GEMM out (dinv-scaled)

    // setup: W convert (blocks 0..159) + bfill zero (block 160)
    wconv_kernel<<<161, 256, 0, stream>>>(W1, W2, W3, wsw1, wsw2, wsw3, bfill);

    int bin_blocks = (E + CHUNK - 1) / CHUNK;
    bin_kernel<<<bin_blocks, 256, 0, stream>>>(src, dst, E, region, bfill);
    build_kernel<<<nbuck, 512, 0, stream>>>(region, bfill, rinfo, dinv, col, n);

    int gemm_blocks = (n + 127) / 128;
    int agg_blocks = 4096;

    // layer 1
    mfma_gemm_kernel<128, true><<<gemm_blocks, 256, 0, stream>>>(x, wsw1, dinv, bufB, n);
    agg_ln_kernel<<<agg_blocks, 256, 0, stream>>>(bufB, rinfo, col, dinv, b1, g1, be1, bufA, n);

    // layer 2
    mfma_gemm_kernel<128, false><<<gemm_blocks, 256, 0, stream>>>(bufA, wsw2, dinv, bufB, n);
    agg_ln_kernel<<<agg_blocks, 256, 0, stream>>>(bufB, rinfo, col, dinv, b2, g2, be2, bufA, n);

    // layer 3
    mfma_gemm_kernel<64, false><<<gemm_blocks, 256, 0, stream>>>(bufA, wsw3, dinv, bufB, n);
    agg64_kernel<<<agg_blocks, 256, 0, stream>>>(bufB, rinfo, col, dinv, b3, (float*)d_out, n);
}

// Round 11
// 254.356 us; speedup vs baseline: 1.2363x; 1.0434x over previous
//
#include <hip/hip_runtime.h>

using short8 = __attribute__((ext_vector_type(8))) short;
using f32x4  = __attribute__((ext_vector_type(4))) float;

#define BSHIFT 9
#define BSIZE  512     // nodes per bucket
#define CAP    12288   // max edges per bucket region (mean 8192)
#define CHUNK  2048    // edges per bin block

// ---------------- bf16 helpers ----------------

__device__ __forceinline__ unsigned int f2bf(float f) {
    unsigned int x = __float_as_uint(f);
    x += 0x7fffu + ((x >> 16) & 1u);  // round-to-nearest-even
    return x >> 16;
}
__device__ __forceinline__ unsigned int pack_bf2(float lo, float hi) {
    return f2bf(lo) | (f2bf(hi) << 16);
}

// ---------------- setup: W fp32 -> bf16 XOR-swizzled [c][k]; block 160 zeroes bfill --------

__global__ void wconv_kernel(const float* __restrict__ W1, const float* __restrict__ W2,
                             const float* __restrict__ W3, unsigned short* __restrict__ o1,
                             unsigned short* __restrict__ o2, unsigned short* __restrict__ o3,
                             int* __restrict__ bfill) {
    if (blockIdx.x == 160) {
        bfill[threadIdx.x] = 0;
        return;
    }
    int i = blockIdx.x * 256 + threadIdx.x;
    const float* W;
    unsigned short* o;
    int ncol, j;
    if (i < 16384)      { W = W1; o = o1; ncol = 128; j = i; }
    else if (i < 32768) { W = W2; o = o2; ncol = 128; j = i - 16384; }
    else if (i < 40960) { W = W3; o = o3; ncol = 64;  j = i - 32768; }
    else return;
    int k = j / ncol, c = j % ncol;
    int byte = (c * 256 + k * 2) ^ ((c & 7) << 4);
    o[byte >> 1] = (unsigned short)f2bf(W[j]);
}

// ---------------- graph prep: bucket binning (packed edges: src | dst_local<<17) ------------

__global__ __launch_bounds__(256) void bin_kernel(
    const int* __restrict__ src, const int* __restrict__ dst, int E,
    int* __restrict__ region, int* __restrict__ bfill) {
    __shared__ int lcnt[256];
    __shared__ int loff[256];
    __shared__ int gbase[256];
    __shared__ int stage[CHUNK];
    __shared__ unsigned short bOf[CHUNK];

    int t = threadIdx.x;
    int e0 = blockIdx.x * CHUNK;
    int cnt = min(CHUNK, E - e0);

    lcnt[t] = 0;
    __syncthreads();

    int s_[8], d_[8], p_[8];
#pragma unroll
    for (int i = 0; i < 8; i++) {
        int e = t + i * 256;
        if (e < cnt) {
            int s = src[e0 + e], d = dst[e0 + e];
            s_[i] = s;
            d_[i] = d;
            p_[i] = atomicAdd(&lcnt[d >> BSHIFT], 1);
        } else {
            d_[i] = -1;
        }
    }
    __syncthreads();

    int v = lcnt[t];
    loff[t] = v;
    __syncthreads();
    for (int off = 1; off < 256; off <<= 1) {
        int u = (t >= off) ? loff[t - off] : 0;
        __syncthreads();
        loff[t] += u;
        __syncthreads();
    }
    int ex = loff[t] - v;
    __syncthreads();
    loff[t] = ex;
    gbase[t] = (v > 0) ? atomicAdd(&bfill[t], v) : 0;
    __syncthreads();

#pragma unroll
    for (int i = 0; i < 8; i++) {
        if (d_[i] >= 0) {
            int b = d_[i] >> BSHIFT;
            int j = loff[b] + p_[i];
            stage[j] = s_[i] | ((d_[i] & (BSIZE - 1)) << 17);
            bOf[j] = (unsigned short)b;
        }
    }
    __syncthreads();

    for (int j = t; j < cnt; j += 256) {
        int b = bOf[j];
        int idx = gbase[b] + (j - loff[b]);
        if (idx < CAP) region[(size_t)b * CAP + idx] = stage[j];
    }
}

// per-bucket: LDS hist -> rinfo(beg,end)/dinv, scatter col into fixed-stride window b*CAP
__global__ __launch_bounds__(512) void build_kernel(
    const int* __restrict__ region, const int* __restrict__ bfill,
    int2* __restrict__ rinfo, float* __restrict__ dinv,
    int* __restrict__ col, int n) {
    __shared__ int cnt[BSIZE];
    __shared__ int excl[BSIZE];
    __shared__ int fill[BSIZE];
    int b = blockIdx.x;
    int t = threadIdx.x;
    int base = b * BSIZE;
    int ecnt = min(bfill[b], CAP);
    int ebase = b * CAP;
    const int* reg = region + (size_t)b * CAP;

    cnt[t] = 0;
    fill[t] = 0;
    __syncthreads();

    for (int i = t; i < ecnt; i += 512) atomicAdd(&cnt[reg[i] >> 17], 1);
    __syncthreads();

    int v = cnt[t];
    excl[t] = v;
    __syncthreads();
    for (int off = 1; off < 512; off <<= 1) {
        int u = (t >= off) ? excl[t - off] : 0;
        __syncthreads();
        excl[t] += u;
        __syncthreads();
    }
    int ex = excl[t] - v;
    __syncthreads();
    excl[t] = ex;
    __syncthreads();

    int node = base + t;
    if (node < n) {
        rinfo[node] = make_int2(ebase + ex, ebase + ex + v);
        dinv[node] = rsqrtf((float)(v + 1));  // +1 self loop
    }

    for (int i = t; i < ecnt; i += 512) {
        int p = reg[i];
        int li = p >> 17;
        int pos = atomicAdd(&fill[li], 1);
        col[ebase + excl[li] + pos] = p & 0x1FFFF;
    }
}

// ---------------- MFMA dense transform + int8 row quantization --------------------------------
// Y8[row] = uint8 row of NCOL feats: ub = round(v/s)+128, s = rowmax/127 stored in scl[row].
// v = (X @ W)[row][c] * dinv[row].

template <int NCOL, bool XF32>
__global__ __launch_bounds__(256) void mfma_gemm_kernel(const void* __restrict__ Xv,
                                                        const unsigned short* __restrict__ Wsw,
                                                        const float* __restrict__ dinv,
                                                        unsigned int* __restrict__ Y8,
                                                        float* __restrict__ scl, int n) {
    constexpr int CF = NCOL / 16;
    __shared__ unsigned short Wt[(size_t)NCOL * 128];

    int t = threadIdx.x;
    {   // flat copy of pre-swizzled W (NCOL*16 uint4)
        const uint4* Wg = (const uint4*)Wsw;
        uint4* Wl = (uint4*)Wt;
        for (int i = t; i < NCOL * 16; i += 256) Wl[i] = Wg[i];
    }
    __syncthreads();

    int wid = t >> 6, l = t & 63;
    int row0 = blockIdx.x * 128;
    int kq = l >> 4;
    const char* Wb = (const char*)Wt;

    for (int rt = 0; rt < 2; rt++) {
        int xr = row0 + (wid * 2 + rt) * 16 + (l & 15);
        int xrc = min(xr, n - 1);

        f32x4 acc[CF];
#pragma unroll
        for (int cf = 0; cf < CF; cf++) acc[cf] = (f32x4){0.f, 0.f, 0.f, 0.f};

#pragma unroll
        for (int ks = 0; ks < 4; ks++) {
            short8 bq;
            if (XF32) {
                const float* Xf = (const float*)Xv + (size_t)xrc * 128 + ks * 32 + kq * 8;
                float4 x0 = ((const float4*)Xf)[0];
                float4 x1 = ((const float4*)Xf)[1];
                unsigned int p0 = pack_bf2(x0.x, x0.y), p1 = pack_bf2(x0.z, x0.w);
                unsigned int p2 = pack_bf2(x1.x, x1.y), p3 = pack_bf2(x1.z, x1.w);
                uint4 u = make_uint4(p0, p1, p2, p3);
                bq = *(const short8*)&u;
            } else {
                const char* Xb = (const char*)Xv + (size_t)xrc * 256 + ks * 64 + kq * 16;
                bq = *(const short8*)Xb;
            }
#pragma unroll
            for (int cf = 0; cf < CF; cf++) {
                int c = cf * 16 + (l & 15);
                int byte = (c * 256 + ks * 64 + kq * 16) ^ ((c & 7) << 4);
                short8 aq = *(const short8*)(Wb + byte);
                acc[cf] = __builtin_amdgcn_mfma_f32_16x16x32_bf16(aq, bq, acc[cf], 0, 0, 0);
            }
        }

        if (xr < n) {
            float dsc = dinv[xr];
            float m = 0.f;
#pragma unroll
            for (int cf = 0; cf < CF; cf++) {
#pragma unroll
                for (int j = 0; j < 4; j++) {
                    float v = acc[cf][j] * dsc;
                    acc[cf][j] = v;
                    m = fmaxf(m, fabsf(v));
                }
            }
            // row absmax across the 4 kq lanes holding this row
            m = fmaxf(m, __shfl_xor(m, 16, 64));
            m = fmaxf(m, __shfl_xor(m, 32, 64));
            float s = m * (1.0f / 127.0f);
            float inv = (m > 0.f) ? 127.0f / m : 0.f;

            unsigned int* Yr = Y8 + (size_t)xr * (NCOL / 4);
#pragma unroll
            for (int cf = 0; cf < CF; cf++) {
                unsigned int pk = 0;
#pragma unroll
                for (int j = 0; j < 4; j++) {
                    int qv = (int)rintf(acc[cf][j] * inv) + 128;
                    qv = min(max(qv, 0), 255);
                    pk |= (unsigned int)qv << (8 * j);
                }
                Yr[cf * 4 + kq] = pk;
            }
            if (kq == 0) scl[xr] = s;
        }
    }
}

// accumulate 8 uint8 feats (packed uint2) with row scale sc; scs accumulates Σsc
#define ACCQ(v, sc)                                          \
    scs += (sc);                                             \
    a0 = fmaf((float)((v).x & 0xffu), (sc), a0);             \
    a1 = fmaf((float)(((v).x >> 8) & 0xffu), (sc), a1);      \
    a2 = fmaf((float)(((v).x >> 16) & 0xffu), (sc), a2);     \
    a3 = fmaf((float)((v).x >> 24), (sc), a3);               \
    a4 = fmaf((float)((v).y & 0xffu), (sc), a4);             \
    a5 = fmaf((float)(((v).y >> 8) & 0xffu), (sc), a5);      \
    a6 = fmaf((float)(((v).y >> 16) & 0xffu), (sc), a6);     \
    a7 = fmaf((float)((v).y >> 24), (sc), a7);

// ---------------- fused aggregate + bias + LayerNorm + ReLU (128 int8 feats -> bf16) --------
// Quarter-wave q; lane l in [0,16) holds feats 8l..8l+7 (uint2 = 8 bytes of the 128B row).
// Streams 8 edges/iter (2 per quarter).

__global__ __launch_bounds__(256) void agg_ln_kernel(
    const unsigned int* __restrict__ tmp, const float* __restrict__ scl,
    const int2* __restrict__ rinfo, const int* __restrict__ col,
    const float* __restrict__ dinv, const float* __restrict__ bias,
    const float* __restrict__ gamma, const float* __restrict__ beta,
    unsigned int* __restrict__ out, int n) {
    int wid = threadIdx.x >> 6;
    int lane = threadIdx.x & 63;
    int q = lane >> 4;
    int l = lane & 15;
    int stride = gridDim.x * 4;

    const uint2* T = (const uint2*)tmp;  // row stride 16 uint2 (128B)

    for (int node = blockIdx.x * 4 + wid; node < n; node += stride) {
        float di = dinv[node];
        int2 be = rinfo[node];
        int beg = __builtin_amdgcn_readfirstlane(be.x);
        int end = __builtin_amdgcn_readfirstlane(be.y);

        float a0 = 0.f, a1 = 0.f, a2 = 0.f, a3 = 0.f;
        float a4 = 0.f, a5 = 0.f, a6 = 0.f, a7 = 0.f;
        float scs = 0.f;
        int e = beg;
#pragma unroll 2
        for (; e + 7 < end; e += 8) {
            int c0 = col[e], c1 = col[e + 1], c2 = col[e + 2], c3 = col[e + 3];
            int c4 = col[e + 4], c5 = col[e + 5], c6 = col[e + 6], c7 = col[e + 7];
            int sa = (q & 1) ? c1 : c0;
            int sb = (q & 1) ? c3 : c2;
            int s1 = (q & 2) ? sb : sa;
            int sc_ = (q & 1) ? c5 : c4;
            int sd = (q & 1) ? c7 : c6;
            int s2 = (q & 2) ? sd : sc_;
            uint2 v1 = T[(size_t)s1 * 16 + l];
            float f1 = scl[s1];
            uint2 v2 = T[(size_t)s2 * 16 + l];
            float f2 = scl[s2];
            ACCQ(v1, f1)
            ACCQ(v2, f2)
        }
        if (e + 3 < end) {
            int c0 = col[e], c1 = col[e + 1], c2 = col[e + 2], c3 = col[e + 3];
            int sa = (q & 1) ? c1 : c0;
            int sb = (q & 1) ? c3 : c2;
            int s = (q & 2) ? sb : sa;
            uint2 v = T[(size_t)s * 16 + l];
            float f = scl[s];
            ACCQ(v, f)
            e += 4;
        }
        int rem = end - e;  // 0..3
        if (q < rem) {
            int s = col[e + q];
            uint2 v = T[(size_t)s * 16 + l];
            float f = scl[s];
            ACCQ(v, f)
        }
        if (q == 3) {  // self loop
            uint2 v = T[(size_t)node * 16 + l];
            float f = scl[node];
            ACCQ(v, f)
        }
        // offset correction: Σ(ub-128)*s = Σ ub*s - 128*Σs  (per quarter, before combine)
        a0 = fmaf(-128.f, scs, a0); a1 = fmaf(-128.f, scs, a1);
        a2 = fmaf(-128.f, scs, a2); a3 = fmaf(-128.f, scs, a3);
        a4 = fmaf(-128.f, scs, a4); a5 = fmaf(-128.f, scs, a5);
        a6 = fmaf(-128.f, scs, a6); a7 = fmaf(-128.f, scs, a7);

        // combine quarters
        a0 += __shfl_xor(a0, 16, 64); a1 += __shfl_xor(a1, 16, 64);
        a2 += __shfl_xor(a2, 16, 64); a3 += __shfl_xor(a3, 16, 64);
        a4 += __shfl_xor(a4, 16, 64); a5 += __shfl_xor(a5, 16, 64);
        a6 += __shfl_xor(a6, 16, 64); a7 += __shfl_xor(a7, 16, 64);
        a0 += __shfl_xor(a0, 32, 64); a1 += __shfl_xor(a1, 32, 64);
        a2 += __shfl_xor(a2, 32, 64); a3 += __shfl_xor(a3, 32, 64);
        a4 += __shfl_xor(a4, 32, 64); a5 += __shfl_xor(a5, 32, 64);
        a6 += __shfl_xor(a6, 32, 64); a7 += __shfl_xor(a7, 32, 64);

        float4 b0 = ((const float4*)bias)[2 * l];
        float4 b1 = ((const float4*)bias)[2 * l + 1];
        a0 = fmaf(a0, di, b0.x); a1 = fmaf(a1, di, b0.y);
        a2 = fmaf(a2, di, b0.z); a3 = fmaf(a3, di, b0.w);
        a4 = fmaf(a4, di, b1.x); a5 = fmaf(a5, di, b1.y);
        a6 = fmaf(a6, di, b1.z); a7 = fmaf(a7, di, b1.w);

        // LayerNorm across 16 lanes (all quarters hold identical data)
        float s8 = a0 + a1 + a2 + a3 + a4 + a5 + a6 + a7;
#pragma unroll
        for (int m = 1; m < 16; m <<= 1) s8 += __shfl_xor(s8, m, 64);
        float mu = s8 * (1.0f / 128.0f);
        float d0 = a0 - mu, d1 = a1 - mu, d2 = a2 - mu, d3 = a3 - mu;
        float d4 = a4 - mu, d5 = a5 - mu, d6 = a6 - mu, d7 = a7 - mu;
        float vv = d0 * d0 + d1 * d1 + d2 * d2 + d3 * d3 +
                   d4 * d4 + d5 * d5 + d6 * d6 + d7 * d7;
#pragma unroll
        for (int m = 1; m < 16; m <<= 1) vv += __shfl_xor(vv, m, 64);
        float r = rsqrtf(vv * (1.0f / 128.0f) + 1e-5f);

        if (lane < 16) {
            float4 g0 = ((const float4*)gamma)[2 * l];
            float4 g1 = ((const float4*)gamma)[2 * l + 1];
            float4 e0 = ((const float4*)beta)[2 * l];
            float4 e1 = ((const float4*)beta)[2 * l + 1];
            float o0 = fmaxf(fmaf(d0 * r, g0.x, e0.x), 0.f);
            float o1 = fmaxf(fmaf(d1 * r, g0.y, e0.y), 0.f);
            float o2 = fmaxf(fmaf(d2 * r, g0.z, e0.z), 0.f);
            float o3 = fmaxf(fmaf(d3 * r, g0.w, e0.w), 0.f);
            float o4 = fmaxf(fmaf(d4 * r, g1.x, e1.x), 0.f);
            float o5 = fmaxf(fmaf(d5 * r, g1.y, e1.y), 0.f);
            float o6 = fmaxf(fmaf(d6 * r, g1.z, e1.z), 0.f);
            float o7 = fmaxf(fmaf(d7 * r, g1.w, e1.w), 0.f);
            uint4 o = make_uint4(pack_bf2(o0, o1), pack_bf2(o2, o3),
                                 pack_bf2(o4, o5), pack_bf2(o6, o7));
            ((uint4*)out)[(size_t)node * 16 + l] = o;
        }
    }
}

// ---------------- final aggregate + bias (64 int8 feats -> fp32, no LN) ----------------
// Eighth-wave oc; lane l in [0,8) holds feats 8l..8l+7 (uint2 of the 64B row).

__global__ __launch_bounds__(256) void agg64_kernel(
    const unsigned int* __restrict__ tmp, const float* __restrict__ scl,
    const int2* __restrict__ rinfo, const int* __restrict__ col,
    const float* __restrict__ dinv, const float* __restrict__ bias,
    float* __restrict__ out, int n) {
    int wid = threadIdx.x >> 6;
    int lane = threadIdx.x & 63;
    int oc = lane >> 3;
    int l = lane & 7;
    int stride = gridDim.x * 4;

    const uint2* T = (const uint2*)tmp;  // row stride 8 uint2 (64B)

    for (int node = blockIdx.x * 4 + wid; node < n; node += stride) {
        float di = dinv[node];
        int2 be = rinfo[node];
        int beg = __builtin_amdgcn_readfirstlane(be.x);
        int end = __builtin_amdgcn_readfirstlane(be.y);

        float a0 = 0.f, a1 = 0.f, a2 = 0.f, a3 = 0.f;
        float a4 = 0.f, a5 = 0.f, a6 = 0.f, a7 = 0.f;
        float scs = 0.f;
        int e = beg;
#pragma unroll 2
        for (; e + 7 < end; e += 8) {
            int c0 = col[e], c1 = col[e + 1], c2 = col[e + 2], c3 = col[e + 3];
            int c4 = col[e + 4], c5 = col[e + 5], c6 = col[e + 6], c7 = col[e + 7];
            int sa = (oc & 1) ? c1 : c0;
            int sb = (oc & 1) ? c3 : c2;
            int sc_ = (oc & 1) ? c5 : c4;
            int sd = (oc & 1) ? c7 : c6;
            int sab = (oc & 2) ? sb : sa;
            int scd = (oc & 2) ? sd : sc_;
            int s = (oc & 4) ? scd : sab;
            uint2 v = T[(size_t)s * 8 + l];
            float f = scl[s];
            ACCQ(v, f)
        }
        int rem = end - e;  // 0..7, oc==7 never takes tail
        if (oc < rem) {
            int s = col[e + oc];
            uint2 v = T[(size_t)s * 8 + l];
            float f = scl[s];
            ACCQ(v, f)
        }
        if (oc == 7) {  // self loop
            uint2 v = T[(size_t)node * 8 + l];
            float f = scl[node];
            ACCQ(v, f)
        }
        a0 = fmaf(-128.f, scs, a0); a1 = fmaf(-128.f, scs, a1);
        a2 = fmaf(-128.f, scs, a2); a3 = fmaf(-128.f, scs, a3);
        a4 = fmaf(-128.f, scs, a4); a5 = fmaf(-128.f, scs, a5);
        a6 = fmaf(-128.f, scs, a6); a7 = fmaf(-128.f, scs, a7);

        a0 += __shfl_xor(a0, 8, 64);  a1 += __shfl_xor(a1, 8, 64);
        a2 += __shfl_xor(a2, 8, 64);  a3 += __shfl_xor(a3, 8, 64);
        a4 += __shfl_xor(a4, 8, 64);  a5 += __shfl_xor(a5, 8, 64);
        a6 += __shfl_xor(a6, 8, 64);  a7 += __shfl_xor(a7, 8, 64);
        a0 += __shfl_xor(a0, 16, 64); a1 += __shfl_xor(a1, 16, 64);
        a2 += __shfl_xor(a2, 16, 64); a3 += __shfl_xor(a3, 16, 64);
        a4 += __shfl_xor(a4, 16, 64); a5 += __shfl_xor(a5, 16, 64);
        a6 += __shfl_xor(a6, 16, 64); a7 += __shfl_xor(a7, 16, 64);
        a0 += __shfl_xor(a0, 32, 64); a1 += __shfl_xor(a1, 32, 64);
        a2 += __shfl_xor(a2, 32, 64); a3 += __shfl_xor(a3, 32, 64);
        a4 += __shfl_xor(a4, 32, 64); a5 += __shfl_xor(a5, 32, 64);
        a6 += __shfl_xor(a6, 32, 64); a7 += __shfl_xor(a7, 32, 64);

        if (lane < 8) {
            float4 b0 = ((const float4*)bias)[2 * l];
            float4 b1 = ((const float4*)bias)[2 * l + 1];
            float4 o0, o1;
            o0.x = fmaf(a0, di, b0.x); o0.y = fmaf(a1, di, b0.y);
            o0.z = fmaf(a2, di, b0.z); o0.w = fmaf(a3, di, b0.w);
            o1.x = fmaf(a4, di, b1.x); o1.y = fmaf(a5, di, b1.y);
            o1.z = fmaf(a6, di, b1.z); o1.w = fmaf(a7, di, b1.w);
            ((float4*)out)[(size_t)node * 16 + 2 * l] = o0;
            ((float4*)out)[(size_t)node * 16 + 2 * l + 1] = o1;
        }
    }
}

// ---------------- launch ----------------

extern "C" void kernel_launch(void* const* d_in, const int* in_sizes, int n_in,
                              void* d_out, int out_size, void* d_ws, size_t ws_size,
                              hipStream_t stream) {
    const float* x   = (const float*)d_in[0];
    const int*   ei  = (const int*)d_in[1];
    const float* W1  = (const float*)d_in[2];
    const float* b1  = (const float*)d_in[3];
    const float* g1  = (const float*)d_in[4];
    const float* be1 = (const float*)d_in[5];
    const float* W2  = (const float*)d_in[6];
    const float* b2  = (const float*)d_in[7];
    const float* g2  = (const float*)d_in[8];
    const float* be2 = (const float*)d_in[9];
    const float* W3  = (const float*)d_in[10];
    const float* b3  = (const float*)d_in[11];

    int n = in_sizes[0] / 128;
    int E = in_sizes[1] / 2;
    const int* src = ei;
    const int* dst = ei + E;
    int nbuck = (n + BSIZE - 1) / BSIZE;  // 196 for n=100000 (n must be < 131072)

    char* p = (char*)d_ws;
    auto alloc = [&](size_t bytes) {
        void* q = (void*)p;
        p += (bytes + 255) & ~(size_t)255;
        return q;
    };
    int*   bfill   = (int*)alloc(256 * 4);
    int2*  rinfo   = (int2*)alloc((size_t)n * 8);
    float* dinv    = (float*)alloc((size_t)n * 4);
    float* scl     = (float*)alloc((size_t)n * 4);
    unsigned short* wsw1 = (unsigned short*)alloc(128 * 128 * 2);
    unsigned short* wsw2 = (unsigned short*)alloc(128 * 128 * 2);
    unsigned short* wsw3 = (unsigned short*)alloc(64 * 128 * 2);
    int*   region  = (int*)alloc((size_t)nbuck * CAP * 4);
    int*   col     = (int*)alloc((size_t)nbuck * CAP * 4);
    unsigned int* bufA = (unsigned int*)alloc((size_t)n * 64 * 4);  // LN out, n x 128 bf16
    unsigned int* bufB = (unsigned int*)alloc((size_t)n * 32 * 4);  // GEMM out, n x 128 int8

    // setup: W convert (blocks 0..159) + bfill zero (block 160)
    wconv_kernel<<<161, 256, 0, stream>>>(W1, W2, W3, wsw1, wsw2, wsw3, bfill);

    int bin_blocks = (E + CHUNK - 1) / CHUNK;
    bin_kernel<<<bin_blocks, 256, 0, stream>>>(src, dst, E, region, bfill);
    build_kernel<<<nbuck, 512, 0, stream>>>(region, bfill, rinfo, dinv, col, n);

    int gemm_blocks = (n + 127) / 128;
    int agg_blocks = 4096;

    // layer 1
    mfma_gemm_kernel<128, true><<<gemm_blocks, 256, 0, stream>>>(x, wsw1, dinv, bufB, scl, n);
    agg_ln_kernel<<<agg_blocks, 256, 0, stream>>>(bufB, scl, rinfo, col, dinv, b1, g1, be1, bufA, n);

    // layer 2
    mfma_gemm_kernel<128, false><<<gemm_blocks, 256, 0, stream>>>(bufA, wsw2, dinv, bufB, scl, n);
    agg_ln_kernel<<<agg_blocks, 256, 0, stream>>>(bufB, scl, rinfo, col, dinv, b2, g2, be2, bufA, n);

    // layer 3
    mfma_gemm_kernel<64, false><<<gemm_blocks, 256, 0, stream>>>(bufA, wsw3, dinv, bufB, scl, n);
    agg64_kernel<<<agg_blocks, 256, 0, stream>>>(bufB, scl, rinfo, col, dinv, b3, (float*)d_out, n);
}